// Round 5
// baseline (1603.629 us; speedup 1.0000x reference)
//
#include <hip/hip_runtime.h>
#include <cstdint>
#include <cstddef>

typedef __attribute__((ext_vector_type(8))) _Float16 half8;
typedef __attribute__((ext_vector_type(4))) float floatx4;

#define NB_MAX 1024  // supports M <= 65536 (M = 50000)

// ---------------- edge dtype detection (int64 vs int32) ----------------
__global__ void detect_i64(const int* __restrict__ ei, int npairs, int* __restrict__ is32) {
  int i = blockIdx.x * blockDim.x + threadIdx.x;
  if (i < npairs && ei[2 * i + 1] != 0) atomicOr(is32, 1);
}

// ---------------- weight prep: [K][128] fp32 -> [128][K] fp16 (transposed) ----------------
__global__ void prep_w_k(const float* __restrict__ W, _Float16* __restrict__ Wt, int K) {
  int i = blockIdx.x * blockDim.x + threadIdx.x;
  if (i < K * 128) {
    int k = i >> 7, n = i & 127;
    Wt[n * K + k] = (_Float16)W[i];
  }
}

// ---------------- bucket histogram (bucket = dst >> 6), LDS pre-aggregated ----------------
__global__ void bucket_hist_k(const int* __restrict__ ei, int E, const int* __restrict__ is32p,
                              int* __restrict__ bcnt, int nb) {
  __shared__ int h[NB_MAX];
  int tid = threadIdx.x;
  for (int i = tid; i < nb; i += 256) h[i] = 0;
  __syncthreads();
  int is32 = *is32p;
  int per = (E + gridDim.x - 1) / gridDim.x;
  int beg = blockIdx.x * per, end = min(beg + per, E);
  for (int e = beg + tid; e < end; e += 256) {
    int dst = is32 ? ei[E + e] : ei[2 * (E + e)];
    atomicAdd(&h[dst >> 6], 1);
  }
  __syncthreads();
  for (int i = tid; i < nb; i += 256) if (h[i]) atomicAdd(&bcnt[i], h[i]);
}

// ---------------- single-block exclusive scan over nb (<=1024) bucket counts ----------------
__global__ void scan_nb_k(const int* __restrict__ bcnt, int* __restrict__ base,
                          int* __restrict__ cursor, int nb) {
  int tid = threadIdx.x;  // 256
  int i0 = tid * 4;
  int v[4]; int s = 0;
#pragma unroll
  for (int j = 0; j < 4; ++j) { int idx = i0 + j; v[j] = (idx < nb) ? bcnt[idx] : 0; s += v[j]; }
  int lane = tid & 63, w = tid >> 6;
  int sc = s;
  for (int d = 1; d < 64; d <<= 1) { int t = __shfl_up(sc, d); if (lane >= d) sc += t; }
  __shared__ int wsum[4];
  if (lane == 63) wsum[w] = sc;
  __syncthreads();
  int add = 0;
  for (int j = 0; j < w; ++j) add += wsum[j];
  int run = add + (sc - s);
#pragma unroll
  for (int j = 0; j < 4; ++j) {
    int idx = i0 + j;
    if (idx < nb) { base[idx] = run; cursor[idx] = run; }
    run += v[j];
  }
  if (tid == 255) base[nb] = add + sc;  // grand total
}

// ---------------- block-aggregated bucket scatter: tmp[pos] = src | dst_local<<26 ----------------
__global__ void epack_k(const int* __restrict__ ei, int E, const int* __restrict__ is32p,
                        int* __restrict__ cursor, unsigned* __restrict__ tmp, int nb) {
  __shared__ int h[NB_MAX];
  __shared__ int lbase[NB_MAX];
  int tid = threadIdx.x;
  for (int i = tid; i < nb; i += 256) h[i] = 0;
  __syncthreads();
  int is32 = *is32p;
  int per = (E + gridDim.x - 1) / gridDim.x;
  int beg = blockIdx.x * per, end = min(beg + per, E);
  for (int e = beg + tid; e < end; e += 256) {
    int dst = is32 ? ei[E + e] : ei[2 * (E + e)];
    atomicAdd(&h[dst >> 6], 1);
  }
  __syncthreads();
  for (int i = tid; i < nb; i += 256) {
    int c = h[i];
    lbase[i] = c ? atomicAdd(&cursor[i], c) : 0;
    h[i] = 0;  // reuse as local cursor
  }
  __syncthreads();
  for (int e = beg + tid; e < end; e += 256) {
    int src = is32 ? ei[e] : ei[2 * e];
    int dst = is32 ? ei[E + e] : ei[2 * (E + e)];
    int b = dst >> 6;
    int lo = atomicAdd(&h[b], 1);
    tmp[lbase[b] + lo] = (unsigned)src | ((unsigned)(dst & 63) << 26);
  }
}

// ---------------- dual GEMM: H = A@W (fp16 out), Rout = A@root + bias (fp32 out) ----------------
// A: [M][K] row-major (fp32 if CVT, fp16 otherwise). Wt/Rt: [128][K] fp16 transposed.
// Block: 256 thr (4 waves), BM=64 rows, BK=64. mfma_f32_16x16x32_f16.
// A/B frags: contiguous 8-elem k-runs (consistent k-relabel both operands -> valid).
// C/D: col=lane&15, row=(lane>>4)*4+reg.
template <int K, bool CVT>
__launch_bounds__(256, 2)
__global__ void gemm_dual_k(const void* __restrict__ Ap, const _Float16* __restrict__ Wt,
                            const _Float16* __restrict__ Rt, const float* __restrict__ bias,
                            _Float16* __restrict__ H, float* __restrict__ Rout, int M) {
  constexpr int LDP = 72;  // 64->72 halfs: row stride 144B -> 2-way banks (free)
  __shared__ _Float16 As[64 * LDP];
  __shared__ _Float16 Bs[128 * LDP];
  __shared__ _Float16 Cs[128 * LDP];
  const int tid = threadIdx.x;
  const int lane = tid & 63;
  const int w = tid >> 6;
  const int m0 = blockIdx.x * 64;
  const int l15 = lane & 15;
  const int hi = lane >> 4;

  floatx4 acc[16];
#pragma unroll
  for (int t = 0; t < 16; ++t) acc[t] = (floatx4)0.f;

  for (int k0 = 0; k0 < K; k0 += 64) {
    __syncthreads();
    // stage A: 64 rows x 64 k
#pragma unroll
    for (int j = 0; j < 2; ++j) {
      int u = tid + 256 * j;
      int row = u >> 3, ks = u & 7;
      int rg = m0 + row; if (rg >= M) rg = M - 1;  // tail clamp; stores masked later
      if constexpr (CVT) {
        const float* A = (const float*)Ap;
        const float* s = A + (size_t)rg * K + k0 + ks * 8;
        float4 a = *(const float4*)s;
        float4 b = *(const float4*)(s + 4);
        half8 v;
        v[0] = (_Float16)a.x; v[1] = (_Float16)a.y; v[2] = (_Float16)a.z; v[3] = (_Float16)a.w;
        v[4] = (_Float16)b.x; v[5] = (_Float16)b.y; v[6] = (_Float16)b.z; v[7] = (_Float16)b.w;
        *(half8*)&As[row * LDP + ks * 8] = v;
      } else {
        const _Float16* A = (const _Float16*)Ap;
        *(half8*)&As[row * LDP + ks * 8] = *(const half8*)(A + (size_t)rg * K + k0 + ks * 8);
      }
    }
    // stage W / root chunks: 128 rows x 64 k each
#pragma unroll
    for (int j = 0; j < 4; ++j) {
      int u = tid + 256 * j;
      int row = u >> 3, ks = u & 7;
      *(half8*)&Bs[row * LDP + ks * 8] = *(const half8*)(Wt + row * K + k0 + ks * 8);
      *(half8*)&Cs[row * LDP + ks * 8] = *(const half8*)(Rt + row * K + k0 + ks * 8);
    }
    __syncthreads();
#pragma unroll
    for (int kk = 0; kk < 2; ++kk) {
      half8 af = *(const half8*)&As[(w * 16 + l15) * LDP + kk * 32 + hi * 8];
#pragma unroll
      for (int t = 0; t < 16; ++t) {
        const _Float16* bp = (t < 8) ? Bs : Cs;
        half8 bf = *(const half8*)&bp[((t & 7) * 16 + l15) * LDP + kk * 32 + hi * 8];
        acc[t] = __builtin_amdgcn_mfma_f32_16x16x32_f16(af, bf, acc[t], 0, 0, 0);
      }
    }
  }
  const int r0 = hi * 4;
#pragma unroll
  for (int t = 0; t < 16; ++t) {
    int n = (t & 7) * 16 + l15;
#pragma unroll
    for (int j = 0; j < 4; ++j) {
      int row = m0 + w * 16 + r0 + j;
      if (row < M) {
        if (t < 8) H[(size_t)row * 128 + n] = (_Float16)acc[t][j];
        else       Rout[(size_t)row * 128 + n] = acc[t][j] + bias[n];
      }
    }
  }
}

// ---------------- fused bucket aggregation + mean + root(+bias) (+relu) ----------------
// One block (256 thr = 4 waves) per bucket of 64 dst nodes. LDS fp32 accum [64][128].
// Lane L owns channels L and L+64 (conflict-free ds_add_f32).
template <bool RELU, typename OutT>
__global__ void agg_bucket(const _Float16* __restrict__ Hh, const float* __restrict__ R,
                           const int* __restrict__ base, const unsigned* __restrict__ tmp,
                           OutT* __restrict__ out, int M) {
  __shared__ float accum[64][128];  // 32KB
  __shared__ int degs[64];
  int b = blockIdx.x;
  int tid = threadIdx.x;
  int lane = tid & 63, wv = tid >> 6;
  for (int i = tid; i < 64 * 128; i += 256) ((float*)accum)[i] = 0.f;
  if (tid < 64) degs[tid] = 0;
  __syncthreads();
  int beg = base[b], end = base[b + 1];
  int e = beg + wv;
  for (; e + 4 < end; e += 8) {  // unroll-2 across this wave's stride-4 stream
    unsigned p0 = tmp[e], p1 = tmp[e + 4];
    int s0 = p0 & 0x3ffffff, d0 = p0 >> 26;
    int s1 = p1 & 0x3ffffff, d1 = p1 >> 26;
    float a0 = (float)Hh[(size_t)s0 * 128 + lane];
    float b0 = (float)Hh[(size_t)s0 * 128 + 64 + lane];
    float a1 = (float)Hh[(size_t)s1 * 128 + lane];
    float b1 = (float)Hh[(size_t)s1 * 128 + 64 + lane];
    atomicAdd(&accum[d0][lane], a0);
    atomicAdd(&accum[d0][64 + lane], b0);
    atomicAdd(&accum[d1][lane], a1);
    atomicAdd(&accum[d1][64 + lane], b1);
    if (lane == 0) { atomicAdd(&degs[d0], 1); atomicAdd(&degs[d1], 1); }
  }
  if (e < end) {
    unsigned p0 = tmp[e];
    int s0 = p0 & 0x3ffffff, d0 = p0 >> 26;
    float a0 = (float)Hh[(size_t)s0 * 128 + lane];
    float b0 = (float)Hh[(size_t)s0 * 128 + 64 + lane];
    atomicAdd(&accum[d0][lane], a0);
    atomicAdd(&accum[d0][64 + lane], b0);
    if (lane == 0) atomicAdd(&degs[d0], 1);
  }
  __syncthreads();
  int n0 = b * 64;
  for (int i = tid; i < 64 * 128; i += 256) {
    int n = i >> 7, c = i & 127;
    int node = n0 + n;
    if (node < M) {
      float d = (float)degs[n];
      float val = accum[n][c] / fmaxf(d, 1.f) + R[(size_t)node * 128 + c];
      if (RELU) val = fmaxf(val, 0.f);
      out[(size_t)node * 128 + c] = (OutT)val;
    }
  }
}

// ---------------- launch ----------------
extern "C" void kernel_launch(void* const* d_in, const int* in_sizes, int n_in,
                              void* d_out, int out_size, void* d_ws, size_t ws_size,
                              hipStream_t stream) {
  const float* x     = (const float*)d_in[0];
  const int*   ei    = (const int*)d_in[1];
  const float* W1    = (const float*)d_in[2];
  const float* root1 = (const float*)d_in[3];
  const float* b1    = (const float*)d_in[4];
  const float* W2    = (const float*)d_in[5];
  const float* root2 = (const float*)d_in[6];
  const float* b2    = (const float*)d_in[7];

  const int M = in_sizes[0] / 256;   // 50000
  const int E = in_sizes[1] / 2;     // 800000
  const int NB = (M + 63) >> 6;      // 782

  char* p = (char*)d_ws;
  auto alloc = [&](size_t b) { char* r = p; p += (b + 255) & ~(size_t)255; return r; };
  _Float16* W1t = (_Float16*)alloc((size_t)128 * 256 * 2);
  _Float16* R1t = (_Float16*)alloc((size_t)128 * 256 * 2);
  _Float16* W2t = (_Float16*)alloc((size_t)128 * 128 * 2);
  _Float16* R2t = (_Float16*)alloc((size_t)128 * 128 * 2);
  _Float16* Hh  = (_Float16*)alloc((size_t)M * 128 * 2);   // messages (reused both layers)
  float*    Rb  = (float*)alloc((size_t)M * 128 * 4);      // root path (reused)
  _Float16* hh  = (_Float16*)alloc((size_t)M * 128 * 2);   // layer-1 activations
  int* is32   = (int*)alloc(4);
  int* bcnt   = (int*)alloc((size_t)NB * 4);
  int* base   = (int*)alloc(((size_t)NB + 1) * 4);
  int* cursor = (int*)alloc((size_t)NB * 4);
  unsigned* tmp = (unsigned*)alloc((size_t)E * 4);

  hipMemsetAsync(is32, 0, 4, stream);
  hipMemsetAsync(bcnt, 0, (size_t)NB * 4, stream);

  detect_i64<<<4, 256, 0, stream>>>(ei, 1024, is32);
  prep_w_k<<<128, 256, 0, stream>>>(W1, W1t, 256);
  prep_w_k<<<128, 256, 0, stream>>>(root1, R1t, 256);
  prep_w_k<<<64, 256, 0, stream>>>(W2, W2t, 128);
  prep_w_k<<<64, 256, 0, stream>>>(root2, R2t, 128);

  bucket_hist_k<<<256, 256, 0, stream>>>(ei, E, is32, bcnt, NB);
  scan_nb_k<<<1, 256, 0, stream>>>(bcnt, base, cursor, NB);
  epack_k<<<128, 256, 0, stream>>>(ei, E, is32, cursor, tmp, NB);

  int gb = (M + 63) / 64;
  gemm_dual_k<256, true><<<gb, 256, 0, stream>>>(x, W1t, R1t, b1, Hh, Rb, M);
  agg_bucket<true, _Float16><<<NB, 256, 0, stream>>>(Hh, Rb, base, tmp, hh, M);
  gemm_dual_k<128, false><<<gb, 256, 0, stream>>>(hh, W2t, R2t, b2, Hh, Rb, M);
  agg_bucket<false, float><<<NB, 256, 0, stream>>>(Hh, Rb, base, tmp, (float*)d_out, M);
}

// Round 6
// 321.472 us; speedup vs baseline: 4.9884x; 4.9884x over previous
//
#include <hip/hip_runtime.h>
#include <cstdint>
#include <cstddef>

typedef __attribute__((ext_vector_type(8))) _Float16 half8;
typedef __attribute__((ext_vector_type(4))) float floatx4;

#define NB_MAX 1024  // supports M <= 65536 (M = 50000)

// ---------------- edge dtype detection (int64 vs int32) ----------------
__global__ void detect_i64(const int* __restrict__ ei, int npairs, int* __restrict__ is32) {
  int i = blockIdx.x * blockDim.x + threadIdx.x;
  if (i < npairs && ei[2 * i + 1] != 0) atomicOr(is32, 1);
}

// ---------------- weight prep: [K][128] fp32 -> [128][K] fp16 (transposed) ----------------
__global__ void prep_w_k(const float* __restrict__ W, _Float16* __restrict__ Wt, int K) {
  int i = blockIdx.x * blockDim.x + threadIdx.x;
  if (i < K * 128) {
    int k = i >> 7, n = i & 127;
    Wt[n * K + k] = (_Float16)W[i];
  }
}

// ---------------- bucket histogram (bucket = dst >> 6), LDS pre-aggregated ----------------
__global__ void bucket_hist_k(const int* __restrict__ ei, int E, const int* __restrict__ is32p,
                              int* __restrict__ bcnt, int nb) {
  __shared__ int h[NB_MAX];
  int tid = threadIdx.x;
  for (int i = tid; i < nb; i += 256) h[i] = 0;
  __syncthreads();
  int is32 = *is32p;
  int per = (E + gridDim.x - 1) / gridDim.x;
  int beg = blockIdx.x * per, end = min(beg + per, E);
  for (int e = beg + tid; e < end; e += 256) {
    int dst = is32 ? ei[E + e] : ei[2 * (E + e)];
    atomicAdd(&h[dst >> 6], 1);
  }
  __syncthreads();
  for (int i = tid; i < nb; i += 256) if (h[i]) atomicAdd(&bcnt[i], h[i]);
}

// ---------------- single-block exclusive scan over nb (<=1024) bucket counts ----------------
__global__ void scan_nb_k(const int* __restrict__ bcnt, int* __restrict__ base,
                          int* __restrict__ cursor, int nb) {
  int tid = threadIdx.x;  // 256
  int i0 = tid * 4;
  int v[4]; int s = 0;
#pragma unroll
  for (int j = 0; j < 4; ++j) { int idx = i0 + j; v[j] = (idx < nb) ? bcnt[idx] : 0; s += v[j]; }
  int lane = tid & 63, w = tid >> 6;
  int sc = s;
  for (int d = 1; d < 64; d <<= 1) { int t = __shfl_up(sc, d); if (lane >= d) sc += t; }
  __shared__ int wsum[4];
  if (lane == 63) wsum[w] = sc;
  __syncthreads();
  int add = 0;
  for (int j = 0; j < w; ++j) add += wsum[j];
  int run = add + (sc - s);
#pragma unroll
  for (int j = 0; j < 4; ++j) {
    int idx = i0 + j;
    if (idx < nb) { base[idx] = run; cursor[idx] = run; }
    run += v[j];
  }
  if (tid == 255) base[nb] = add + sc;  // grand total
}

// ---------------- block-aggregated bucket scatter: tmp[pos] = src | dst_local<<26 ----------------
__global__ void epack_k(const int* __restrict__ ei, int E, const int* __restrict__ is32p,
                        int* __restrict__ cursor, unsigned* __restrict__ tmp, int nb) {
  __shared__ int h[NB_MAX];
  __shared__ int lbase[NB_MAX];
  int tid = threadIdx.x;
  for (int i = tid; i < nb; i += 256) h[i] = 0;
  __syncthreads();
  int is32 = *is32p;
  int per = (E + gridDim.x - 1) / gridDim.x;
  int beg = blockIdx.x * per, end = min(beg + per, E);
  for (int e = beg + tid; e < end; e += 256) {
    int dst = is32 ? ei[E + e] : ei[2 * (E + e)];
    atomicAdd(&h[dst >> 6], 1);
  }
  __syncthreads();
  for (int i = tid; i < nb; i += 256) {
    int c = h[i];
    lbase[i] = c ? atomicAdd(&cursor[i], c) : 0;
    h[i] = 0;  // reuse as local cursor
  }
  __syncthreads();
  for (int e = beg + tid; e < end; e += 256) {
    int src = is32 ? ei[e] : ei[2 * e];
    int dst = is32 ? ei[E + e] : ei[2 * (E + e)];
    int b = dst >> 6;
    int lo = atomicAdd(&h[b], 1);
    tmp[lbase[b] + lo] = (unsigned)src | ((unsigned)(dst & 63) << 26);
  }
}

// ---------------- per-bucket counting-sort: tmp -> per-node CSR + per-node offs ----------------
// One block per bucket. Writes land random only within the bucket's ~4KB csr window
// (L2-resident, ~1x write amplification) and node-offsets offs[b*64+ln].
__global__ void local_sort_k(const unsigned* __restrict__ tmp, const int* __restrict__ base,
                             int* __restrict__ csr, int* __restrict__ offs) {
  __shared__ int cnt[64];
  int b = blockIdx.x;
  int tid = threadIdx.x;  // 256
  int beg = base[b], end = base[b + 1];
  if (tid < 64) cnt[tid] = 0;
  __syncthreads();
  for (int e = beg + tid; e < end; e += 256) {
    unsigned p = tmp[e];
    atomicAdd(&cnt[p >> 26], 1);
  }
  __syncthreads();
  if (tid < 64) {  // wave 0: exclusive scan of 64 counts
    int v = cnt[tid];
    int sc = v;
    for (int d = 1; d < 64; d <<= 1) { int t = __shfl_up(sc, d); if (tid >= d) sc += t; }
    int excl = sc - v;
    offs[b * 64 + tid] = beg + excl;   // per-node start (node = b*64+tid)
    cnt[tid] = excl;                   // reuse as local cursor
  }
  __syncthreads();
  for (int e = beg + tid; e < end; e += 256) {
    unsigned p = tmp[e];
    int d = p >> 26;
    int lo = atomicAdd(&cnt[d], 1);
    csr[beg + lo] = (int)(p & 0x3ffffff);
  }
}

// ---------------- dual GEMM: H = A@W (fp16 out), Rout = A@root + bias (fp32 out) ----------------
// A: [M][K] row-major (fp32 if CVT, fp16 otherwise). Wt/Rt: [128][K] fp16 transposed.
// Block: 256 thr (4 waves), BM=64 rows, BK=64. mfma_f32_16x16x32_f16.
// A/B frags: contiguous 8-elem k-runs (consistent k-relabel both operands -> valid).
// C/D: col=lane&15, row=(lane>>4)*4+reg.
template <int K, bool CVT>
__launch_bounds__(256, 2)
__global__ void gemm_dual_k(const void* __restrict__ Ap, const _Float16* __restrict__ Wt,
                            const _Float16* __restrict__ Rt, const float* __restrict__ bias,
                            _Float16* __restrict__ H, float* __restrict__ Rout, int M) {
  constexpr int LDP = 72;  // 64->72 halfs: row stride 144B -> 2-way banks (free)
  __shared__ _Float16 As[64 * LDP];
  __shared__ _Float16 Bs[128 * LDP];
  __shared__ _Float16 Cs[128 * LDP];
  const int tid = threadIdx.x;
  const int lane = tid & 63;
  const int w = tid >> 6;
  const int m0 = blockIdx.x * 64;
  const int l15 = lane & 15;
  const int hi = lane >> 4;

  floatx4 acc[16];
#pragma unroll
  for (int t = 0; t < 16; ++t) acc[t] = (floatx4)0.f;

  for (int k0 = 0; k0 < K; k0 += 64) {
    __syncthreads();
    // stage A: 64 rows x 64 k
#pragma unroll
    for (int j = 0; j < 2; ++j) {
      int u = tid + 256 * j;
      int row = u >> 3, ks = u & 7;
      int rg = m0 + row; if (rg >= M) rg = M - 1;  // tail clamp; stores masked later
      if constexpr (CVT) {
        const float* A = (const float*)Ap;
        const float* s = A + (size_t)rg * K + k0 + ks * 8;
        float4 a = *(const float4*)s;
        float4 b = *(const float4*)(s + 4);
        half8 v;
        v[0] = (_Float16)a.x; v[1] = (_Float16)a.y; v[2] = (_Float16)a.z; v[3] = (_Float16)a.w;
        v[4] = (_Float16)b.x; v[5] = (_Float16)b.y; v[6] = (_Float16)b.z; v[7] = (_Float16)b.w;
        *(half8*)&As[row * LDP + ks * 8] = v;
      } else {
        const _Float16* A = (const _Float16*)Ap;
        *(half8*)&As[row * LDP + ks * 8] = *(const half8*)(A + (size_t)rg * K + k0 + ks * 8);
      }
    }
    // stage W / root chunks: 128 rows x 64 k each
#pragma unroll
    for (int j = 0; j < 4; ++j) {
      int u = tid + 256 * j;
      int row = u >> 3, ks = u & 7;
      *(half8*)&Bs[row * LDP + ks * 8] = *(const half8*)(Wt + row * K + k0 + ks * 8);
      *(half8*)&Cs[row * LDP + ks * 8] = *(const half8*)(Rt + row * K + k0 + ks * 8);
    }
    __syncthreads();
#pragma unroll
    for (int kk = 0; kk < 2; ++kk) {
      half8 af = *(const half8*)&As[(w * 16 + l15) * LDP + kk * 32 + hi * 8];
#pragma unroll
      for (int t = 0; t < 16; ++t) {
        const _Float16* bp = (t < 8) ? Bs : Cs;
        half8 bf = *(const half8*)&bp[((t & 7) * 16 + l15) * LDP + kk * 32 + hi * 8];
        acc[t] = __builtin_amdgcn_mfma_f32_16x16x32_f16(af, bf, acc[t], 0, 0, 0);
      }
    }
  }
  const int r0 = hi * 4;
#pragma unroll
  for (int t = 0; t < 16; ++t) {
    int n = (t & 7) * 16 + l15;
#pragma unroll
    for (int j = 0; j < 4; ++j) {
      int row = m0 + w * 16 + r0 + j;
      if (row < M) {
        if (t < 8) H[(size_t)row * 128 + n] = (_Float16)acc[t][j];
        else       Rout[(size_t)row * 128 + n] = acc[t][j] + bias[n];
      }
    }
  }
}

// ---------------- per-node aggregation + mean + root(+bias) (+relu) ----------------
// One block (128 thr = 2 waves) per dst node; thread c owns channel c. unroll-4 MLP.
template <bool RELU, typename OutT>
__global__ void agg_node_k(const _Float16* __restrict__ Hh, const float* __restrict__ R,
                           const int* __restrict__ offs, const int* __restrict__ csr,
                           OutT* __restrict__ out) {
  int node = blockIdx.x;
  int c = threadIdx.x;
  int beg = offs[node], end = offs[node + 1];
  float acc = 0.f;
  int e = beg;
  for (; e + 4 <= end; e += 4) {
    int s0 = csr[e], s1 = csr[e + 1], s2 = csr[e + 2], s3 = csr[e + 3];
    float a0 = (float)Hh[(size_t)s0 * 128 + c];
    float a1 = (float)Hh[(size_t)s1 * 128 + c];
    float a2 = (float)Hh[(size_t)s2 * 128 + c];
    float a3 = (float)Hh[(size_t)s3 * 128 + c];
    acc += (a0 + a1) + (a2 + a3);
  }
  for (; e < end; ++e) acc += (float)Hh[(size_t)csr[e] * 128 + c];
  float deg = (float)(end - beg);
  float val = acc / fmaxf(deg, 1.f) + R[(size_t)node * 128 + c];
  if (RELU) val = fmaxf(val, 0.f);
  out[(size_t)node * 128 + c] = (OutT)val;
}

// ---------------- launch ----------------
extern "C" void kernel_launch(void* const* d_in, const int* in_sizes, int n_in,
                              void* d_out, int out_size, void* d_ws, size_t ws_size,
                              hipStream_t stream) {
  const float* x     = (const float*)d_in[0];
  const int*   ei    = (const int*)d_in[1];
  const float* W1    = (const float*)d_in[2];
  const float* root1 = (const float*)d_in[3];
  const float* b1    = (const float*)d_in[4];
  const float* W2    = (const float*)d_in[5];
  const float* root2 = (const float*)d_in[6];
  const float* b2    = (const float*)d_in[7];

  const int M = in_sizes[0] / 256;   // 50000
  const int E = in_sizes[1] / 2;     // 800000
  const int NB = (M + 63) >> 6;      // 782

  char* p = (char*)d_ws;
  auto alloc = [&](size_t b) { char* r = p; p += (b + 255) & ~(size_t)255; return r; };
  _Float16* W1t = (_Float16*)alloc((size_t)128 * 256 * 2);
  _Float16* R1t = (_Float16*)alloc((size_t)128 * 256 * 2);
  _Float16* W2t = (_Float16*)alloc((size_t)128 * 128 * 2);
  _Float16* R2t = (_Float16*)alloc((size_t)128 * 128 * 2);
  _Float16* Hh  = (_Float16*)alloc((size_t)M * 128 * 2);   // messages (reused both layers)
  float*    Rb  = (float*)alloc((size_t)M * 128 * 4);      // root path (reused)
  _Float16* hh  = (_Float16*)alloc((size_t)M * 128 * 2);   // layer-1 activations
  int* is32   = (int*)alloc(4);
  int* bcnt   = (int*)alloc((size_t)NB * 4);
  int* base   = (int*)alloc(((size_t)NB + 1) * 4);
  int* cursor = (int*)alloc((size_t)NB * 4);
  int* offs   = (int*)alloc(((size_t)NB * 64 + 64) * 4);   // per-node starts (padded tail)
  unsigned* tmp = (unsigned*)alloc((size_t)E * 4);
  int* csr    = (int*)alloc((size_t)E * 4);

  hipMemsetAsync(is32, 0, 4, stream);
  hipMemsetAsync(bcnt, 0, (size_t)NB * 4, stream);

  detect_i64<<<4, 256, 0, stream>>>(ei, 1024, is32);
  prep_w_k<<<128, 256, 0, stream>>>(W1, W1t, 256);
  prep_w_k<<<128, 256, 0, stream>>>(root1, R1t, 256);
  prep_w_k<<<64, 256, 0, stream>>>(W2, W2t, 128);
  prep_w_k<<<64, 256, 0, stream>>>(root2, R2t, 128);

  bucket_hist_k<<<256, 256, 0, stream>>>(ei, E, is32, bcnt, NB);
  scan_nb_k<<<1, 256, 0, stream>>>(bcnt, base, cursor, NB);
  epack_k<<<128, 256, 0, stream>>>(ei, E, is32, cursor, tmp, NB);
  local_sort_k<<<NB, 256, 0, stream>>>(tmp, base, csr, offs);

  int gb = (M + 63) / 64;
  gemm_dual_k<256, true><<<gb, 256, 0, stream>>>(x, W1t, R1t, b1, Hh, Rb, M);
  agg_node_k<true, _Float16><<<M, 128, 0, stream>>>(Hh, Rb, offs, csr, hh);
  gemm_dual_k<128, false><<<gb, 256, 0, stream>>>(hh, W2t, R2t, b2, Hh, Rb, M);
  agg_node_k<false, float><<<M, 128, 0, stream>>>(Hh, Rb, offs, csr, (float*)d_out);
}

// Round 10
// 307.126 us; speedup vs baseline: 5.2214x; 1.0467x over previous
//
#include <hip/hip_runtime.h>
#include <cstdint>
#include <cstddef>

typedef __attribute__((ext_vector_type(8))) _Float16 half8;
typedef __attribute__((ext_vector_type(4))) _Float16 half4;
typedef __attribute__((ext_vector_type(4))) float floatx4;

#define NB_MAX 1024  // supports M <= 65536 (M = 50000)

// ---------------- edge dtype detection (int64 vs int32) ----------------
__global__ void detect_i64(const int* __restrict__ ei, int npairs, int* __restrict__ is32) {
  int i = blockIdx.x * blockDim.x + threadIdx.x;
  if (i < npairs && ei[2 * i + 1] != 0) atomicOr(is32, 1);
}

// ---------------- weight prep: [K][128] fp32 -> [128][K] fp16 (transposed) ----------------
__global__ void prep_w_k(const float* __restrict__ W, _Float16* __restrict__ Wt, int K) {
  int i = blockIdx.x * blockDim.x + threadIdx.x;
  if (i < K * 128) {
    int k = i >> 7, n = i & 127;
    Wt[n * K + k] = (_Float16)W[i];
  }
}

// ---------------- bucket histogram (bucket = dst >> 6), LDS pre-aggregated ----------------
__global__ void bucket_hist_k(const int* __restrict__ ei, int E, const int* __restrict__ is32p,
                              int* __restrict__ bcnt, int nb) {
  __shared__ int h[NB_MAX];
  int tid = threadIdx.x;
  for (int i = tid; i < nb; i += 256) h[i] = 0;
  __syncthreads();
  int is32 = *is32p;
  int per = (E + gridDim.x - 1) / gridDim.x;
  int beg = blockIdx.x * per, end = min(beg + per, E);
  for (int e = beg + tid; e < end; e += 256) {
    int dst = is32 ? ei[E + e] : ei[2 * (E + e)];
    atomicAdd(&h[dst >> 6], 1);
  }
  __syncthreads();
  for (int i = tid; i < nb; i += 256) if (h[i]) atomicAdd(&bcnt[i], h[i]);
}

// ---------------- single-block exclusive scan over nb (<=1024) bucket counts ----------------
__global__ void scan_nb_k(const int* __restrict__ bcnt, int* __restrict__ base,
                          int* __restrict__ cursor, int nb) {
  int tid = threadIdx.x;  // 256
  int i0 = tid * 4;
  int v[4]; int s = 0;
#pragma unroll
  for (int j = 0; j < 4; ++j) { int idx = i0 + j; v[j] = (idx < nb) ? bcnt[idx] : 0; s += v[j]; }
  int lane = tid & 63, w = tid >> 6;
  int sc = s;
  for (int d = 1; d < 64; d <<= 1) { int t = __shfl_up(sc, d); if (lane >= d) sc += t; }
  __shared__ int wsum[4];
  if (lane == 63) wsum[w] = sc;
  __syncthreads();
  int add = 0;
  for (int j = 0; j < w; ++j) add += wsum[j];
  int run = add + (sc - s);
#pragma unroll
  for (int j = 0; j < 4; ++j) {
    int idx = i0 + j;
    if (idx < nb) { base[idx] = run; cursor[idx] = run; }
    run += v[j];
  }
  if (tid == 255) base[nb] = add + sc;  // grand total
}

// ---------------- block-aggregated bucket scatter: tmp[pos] = src | dst_local<<26 ----------------
__global__ void epack_k(const int* __restrict__ ei, int E, const int* __restrict__ is32p,
                        int* __restrict__ cursor, unsigned* __restrict__ tmp, int nb) {
  __shared__ int h[NB_MAX];
  __shared__ int lbase[NB_MAX];
  int tid = threadIdx.x;
  for (int i = tid; i < nb; i += 256) h[i] = 0;
  __syncthreads();
  int is32 = *is32p;
  int per = (E + gridDim.x - 1) / gridDim.x;
  int beg = blockIdx.x * per, end = min(beg + per, E);
  for (int e = beg + tid; e < end; e += 256) {
    int dst = is32 ? ei[E + e] : ei[2 * (E + e)];
    atomicAdd(&h[dst >> 6], 1);
  }
  __syncthreads();
  for (int i = tid; i < nb; i += 256) {
    int c = h[i];
    lbase[i] = c ? atomicAdd(&cursor[i], c) : 0;
    h[i] = 0;  // reuse as local cursor
  }
  __syncthreads();
  for (int e = beg + tid; e < end; e += 256) {
    int src = is32 ? ei[e] : ei[2 * e];
    int dst = is32 ? ei[E + e] : ei[2 * (E + e)];
    int b = dst >> 6;
    int lo = atomicAdd(&h[b], 1);
    tmp[lbase[b] + lo] = (unsigned)src | ((unsigned)(dst & 63) << 26);
  }
}

// ---------------- per-bucket counting-sort: tmp -> per-node CSR + per-node offs ----------------
__global__ void local_sort_k(const unsigned* __restrict__ tmp, const int* __restrict__ base,
                             int* __restrict__ csr, int* __restrict__ offs) {
  __shared__ int cnt[64];
  int b = blockIdx.x;
  int tid = threadIdx.x;  // 256
  int beg = base[b], end = base[b + 1];
  if (tid < 64) cnt[tid] = 0;
  __syncthreads();
  for (int e = beg + tid; e < end; e += 256) {
    unsigned p = tmp[e];
    atomicAdd(&cnt[p >> 26], 1);
  }
  __syncthreads();
  if (tid < 64) {  // wave 0: exclusive scan of 64 counts
    int v = cnt[tid];
    int sc = v;
    for (int d = 1; d < 64; d <<= 1) { int t = __shfl_up(sc, d); if (tid >= d) sc += t; }
    int excl = sc - v;
    offs[b * 64 + tid] = beg + excl;   // per-node start (node = b*64+tid)
    cnt[tid] = excl;                   // reuse as local cursor
  }
  __syncthreads();
  for (int e = beg + tid; e < end; e += 256) {
    unsigned p = tmp[e];
    int d = p >> 26;
    int lo = atomicAdd(&cnt[d], 1);
    csr[beg + lo] = (int)(p & 0x3ffffff);
  }
}

// ---------------- persistent-weight dual GEMM ----------------
// H = A@W (fp16), Rout = A@root + bias (fp16). WR: [256][K] fp16 (rows 0-127 = W^T,
// rows 128-255 = root^T). Weights staged to LDS ONCE per block; grid-strided M-tiles
// of BM=64 with double-buffered BK=32 A-tile (1 barrier per K-step -> HBM-bound on A).
// 512 thr = 8 waves: wave w owns (row-group w&1 [32 rows], n-quarter w>>1 [64 cols]).
// mfma_f32_16x16x32_f16, frags = contiguous 8-elem k-runs (consistent both operands).
// C/D: col=lane&15, row=(lane>>4)*4+reg (proven layout from R1-R6 kernels).
template <int K, bool CVT>
__launch_bounds__(512, 2)
__global__ void gemm_dual2_k(const void* __restrict__ Ap, const _Float16* __restrict__ WR,
                             const float* __restrict__ bias,
                             _Float16* __restrict__ H, _Float16* __restrict__ Rout,
                             int M, int ntiles) {
  constexpr int LDK = K + 8;   // +16B pad: row stride 528B/272B -> 2-way banks (free)
  constexpr int LDA = 40;      // 32+8 halfs
  __shared__ _Float16 Ws[256 * LDK];      // 132 KB (K=256) / 68 KB (K=128)
  __shared__ _Float16 As[2][64 * LDA];    // 10 KB double-buffered A tile
  const int tid = threadIdx.x;
  const int lane = tid & 63;
  const int w = tid >> 6;
  const int l15 = lane & 15;
  const int hi = lane >> 4;
  const int rg = w & 1;        // row-group (32 rows)
  const int nq = w >> 1;       // n-quarter (4 n-tiles of 16)

  // stage weights once (coalesced 16B)
  for (int i = tid; i < 256 * (K / 8); i += 512) {
    int row = i / (K / 8), ks = i % (K / 8);
    *(half8*)&Ws[row * LDK + ks * 8] = *(const half8*)(WR + (size_t)row * K + ks * 8);
  }
  // per-lane bias for the root half (n >= 128 <=> nq >= 2)
  float biasv[4];
#pragma unroll
  for (int nt = 0; nt < 4; ++nt)
    biasv[nt] = (nq >= 2) ? bias[nq * 64 + nt * 16 + l15 - 128] : 0.f;

  floatx4 acc[2][4];
#pragma unroll
  for (int i = 0; i < 2; ++i)
#pragma unroll
    for (int nt = 0; nt < 4; ++nt) acc[i][nt] = (floatx4)0.f;

  constexpr int NK = K / 32;

  auto stageA = [&](int buf, int m0, int kb) {
    if constexpr (CVT) {
      // 512 thr x 4 f32: 64 rows x 32 k fp32 -> fp16
      int row = tid >> 3, ks = tid & 7;
      int rgl = m0 + row; if (rgl >= M) rgl = M - 1;
      const float* s = (const float*)Ap + (size_t)rgl * K + kb * 32 + ks * 4;
      float4 a = *(const float4*)s;
      half4 v;
      v[0] = (_Float16)a.x; v[1] = (_Float16)a.y; v[2] = (_Float16)a.z; v[3] = (_Float16)a.w;
      *(half4*)&As[buf][row * LDA + ks * 4] = v;
    } else {
      if (tid < 256) {
        int row = tid >> 2, ks = tid & 3;
        int rgl = m0 + row; if (rgl >= M) rgl = M - 1;
        *(half8*)&As[buf][row * LDA + ks * 8] =
            *(const half8*)((const _Float16*)Ap + (size_t)rgl * K + kb * 32 + ks * 8);
      }
    }
  };

  for (int tile = blockIdx.x; tile < ntiles; tile += gridDim.x) {
    const int m0 = tile * 64;
    stageA(0, m0, 0);
    for (int kb = 0; kb < NK; ++kb) {
      __syncthreads();                       // stage(kb) visible; compute(kb-1) done
      if (kb + 1 < NK) stageA((kb + 1) & 1, m0, kb + 1);
      const _Float16* Ab = As[kb & 1];
      half8 af0 = *(const half8*)&Ab[(rg * 32 + l15) * LDA + hi * 8];
      half8 af1 = *(const half8*)&Ab[(rg * 32 + 16 + l15) * LDA + hi * 8];
#pragma unroll
      for (int nt = 0; nt < 4; ++nt) {
        half8 bf = *(const half8*)&Ws[((nq * 4 + nt) * 16 + l15) * LDK + kb * 32 + hi * 8];
        acc[0][nt] = __builtin_amdgcn_mfma_f32_16x16x32_f16(af0, bf, acc[0][nt], 0, 0, 0);
        acc[1][nt] = __builtin_amdgcn_mfma_f32_16x16x32_f16(af1, bf, acc[1][nt], 0, 0, 0);
      }
    }
    // epilogue (global only; no LDS hazard with next tile's stageA)
#pragma unroll
    for (int i = 0; i < 2; ++i)
#pragma unroll
      for (int nt = 0; nt < 4; ++nt) {
        int n = nq * 64 + nt * 16 + l15;
#pragma unroll
        for (int j = 0; j < 4; ++j) {
          int row = m0 + rg * 32 + i * 16 + hi * 4 + j;
          if (row < M) {
            if (n < 128) H[(size_t)row * 128 + n] = (_Float16)acc[i][nt][j];
            else Rout[(size_t)row * 128 + n - 128] = (_Float16)(acc[i][nt][j] + biasv[nt]);
          }
        }
        acc[i][nt] = (floatx4)0.f;
      }
  }
}

// ---------------- per-node aggregation + mean + root(+bias) (+relu) ----------------
// One block (128 thr) per dst node; thread c owns channel c. unroll-4 MLP.
template <bool RELU, typename OutT>
__global__ void agg_node_k(const _Float16* __restrict__ Hh, const _Float16* __restrict__ R,
                           const int* __restrict__ offs, const int* __restrict__ csr,
                           OutT* __restrict__ out) {
  int node = blockIdx.x;
  int c = threadIdx.x;
  int beg = offs[node], end = offs[node + 1];
  float acc = 0.f;
  int e = beg;
  for (; e + 4 <= end; e += 4) {
    int s0 = csr[e], s1 = csr[e + 1], s2 = csr[e + 2], s3 = csr[e + 3];
    float a0 = (float)Hh[(size_t)s0 * 128 + c];
    float a1 = (float)Hh[(size_t)s1 * 128 + c];
    float a2 = (float)Hh[(size_t)s2 * 128 + c];
    float a3 = (float)Hh[(size_t)s3 * 128 + c];
    acc += (a0 + a1) + (a2 + a3);
  }
  for (; e < end; ++e) acc += (float)Hh[(size_t)csr[e] * 128 + c];
  float deg = (float)(end - beg);
  float val = acc / fmaxf(deg, 1.f) + (float)R[(size_t)node * 128 + c];
  if (RELU) val = fmaxf(val, 0.f);
  out[(size_t)node * 128 + c] = (OutT)val;
}

// ---------------- launch ----------------
extern "C" void kernel_launch(void* const* d_in, const int* in_sizes, int n_in,
                              void* d_out, int out_size, void* d_ws, size_t ws_size,
                              hipStream_t stream) {
  const float* x     = (const float*)d_in[0];
  const int*   ei    = (const int*)d_in[1];
  const float* W1    = (const float*)d_in[2];
  const float* root1 = (const float*)d_in[3];
  const float* b1    = (const float*)d_in[4];
  const float* W2    = (const float*)d_in[5];
  const float* root2 = (const float*)d_in[6];
  const float* b2    = (const float*)d_in[7];

  const int M = in_sizes[0] / 256;   // 50000
  const int E = in_sizes[1] / 2;     // 800000
  const int NB = (M + 63) >> 6;      // 782

  char* p = (char*)d_ws;
  auto alloc = [&](size_t b) { char* r = p; p += (b + 255) & ~(size_t)255; return r; };
  _Float16* WR1 = (_Float16*)alloc((size_t)256 * 256 * 2);  // [W1^T ; root1^T]
  _Float16* WR2 = (_Float16*)alloc((size_t)256 * 128 * 2);  // [W2^T ; root2^T]
  _Float16* Hh  = (_Float16*)alloc((size_t)M * 128 * 2);    // messages (reused both layers)
  _Float16* Rb  = (_Float16*)alloc((size_t)M * 128 * 2);    // root path (fp16, reused)
  _Float16* hh  = (_Float16*)alloc((size_t)M * 128 * 2);    // layer-1 activations
  int* is32   = (int*)alloc(4);
  int* bcnt   = (int*)alloc((size_t)NB * 4);
  int* base   = (int*)alloc(((size_t)NB + 1) * 4);
  int* cursor = (int*)alloc((size_t)NB * 4);
  int* offs   = (int*)alloc(((size_t)NB * 64 + 64) * 4);    // per-node starts (padded tail)
  unsigned* tmp = (unsigned*)alloc((size_t)E * 4);
  int* csr    = (int*)alloc((size_t)E * 4);

  hipMemsetAsync(is32, 0, 4, stream);
  hipMemsetAsync(bcnt, 0, (size_t)NB * 4, stream);

  detect_i64<<<4, 256, 0, stream>>>(ei, 1024, is32);
  prep_w_k<<<128, 256, 0, stream>>>(W1, WR1, 256);
  prep_w_k<<<128, 256, 0, stream>>>(root1, WR1 + (size_t)128 * 256, 256);
  prep_w_k<<<64, 256, 0, stream>>>(W2, WR2, 128);
  prep_w_k<<<64, 256, 0, stream>>>(root2, WR2 + (size_t)128 * 128, 128);

  bucket_hist_k<<<256, 256, 0, stream>>>(ei, E, is32, bcnt, NB);
  scan_nb_k<<<1, 256, 0, stream>>>(bcnt, base, cursor, NB);
  epack_k<<<128, 256, 0, stream>>>(ei, E, is32, cursor, tmp, NB);
  local_sort_k<<<NB, 256, 0, stream>>>(tmp, base, csr, offs);

  const int ntiles = (M + 63) / 64;  // 782
  gemm_dual2_k<256, true><<<256, 512, 0, stream>>>(x, WR1, b1, Hh, Rb, M, ntiles);
  agg_node_k<true, _Float16><<<M, 128, 0, stream>>>(Hh, Rb, offs, csr, hh);
  gemm_dual2_k<128, false><<<256, 512, 0, stream>>>(hh, WR2, b2, Hh, Rb, M, ntiles);
  agg_node_k<false, float><<<M, 128, 0, stream>>>(Hh, Rb, offs, csr, (float*)d_out);
}

// Round 11
// 299.303 us; speedup vs baseline: 5.3579x; 1.0261x over previous
//
#include <hip/hip_runtime.h>
#include <cstdint>
#include <cstddef>

typedef __attribute__((ext_vector_type(8))) _Float16 half8;
typedef __attribute__((ext_vector_type(4))) float floatx4;

#define NB_MAX 1024  // supports M <= 65536 (M = 50000)

// async global->LDS, 16B per lane (dest = wave-uniform base + lane*16)
__device__ __forceinline__ void gload_lds16(const void* g, void* l) {
  __builtin_amdgcn_global_load_lds(
      (const __attribute__((address_space(1))) uint32_t*)g,
      (__attribute__((address_space(3))) uint32_t*)l, 16, 0, 0);
}

// ---------------- edge dtype detection (int64 vs int32) ----------------
__global__ void detect_i64(const int* __restrict__ ei, int npairs, int* __restrict__ is32) {
  int i = blockIdx.x * blockDim.x + threadIdx.x;
  if (i < npairs && ei[2 * i + 1] != 0) atomicOr(is32, 1);
}

// ---------------- weight prep: [K][128] fp32 -> [128][K] fp16 (transposed) ----------------
__global__ void prep_w_k(const float* __restrict__ W, _Float16* __restrict__ Wt, int K) {
  int i = blockIdx.x * blockDim.x + threadIdx.x;
  if (i < K * 128) {
    int k = i >> 7, n = i & 127;
    Wt[n * K + k] = (_Float16)W[i];
  }
}

// ---------------- x fp32 -> fp16, PRE-SWIZZLED rows (h ^= (row&7)<<3) ----------------
// The swizzle makes gemm's ds_read_b128 A-frag reads bank-conflict-free while the
// global_load_lds staging stays linear (rule: both-sides-or-neither, m201 pattern).
__global__ void cvt_swz_k(const float* __restrict__ in, _Float16* __restrict__ out, int M) {
  int i = blockIdx.x * blockDim.x + threadIdx.x;  // one thread per 8 halfs
  int r = i >> 5, j = i & 31;
  if (r >= M) return;
  const float* s = in + (size_t)r * 256 + j * 8;
  float4 a = *(const float4*)s;
  float4 b = *(const float4*)(s + 4);
  half8 v;
  v[0] = (_Float16)a.x; v[1] = (_Float16)a.y; v[2] = (_Float16)a.z; v[3] = (_Float16)a.w;
  v[4] = (_Float16)b.x; v[5] = (_Float16)b.y; v[6] = (_Float16)b.z; v[7] = (_Float16)b.w;
  int h0 = (j * 8) ^ ((r & 7) << 3);
  *(half8*)(out + (size_t)r * 256 + h0) = v;
}

// ---------------- bucket histogram (bucket = dst >> 6), LDS pre-aggregated ----------------
__global__ void bucket_hist_k(const int* __restrict__ ei, int E, const int* __restrict__ is32p,
                              int* __restrict__ bcnt, int nb) {
  __shared__ int h[NB_MAX];
  int tid = threadIdx.x;
  for (int i = tid; i < nb; i += 256) h[i] = 0;
  __syncthreads();
  int is32 = *is32p;
  int per = (E + gridDim.x - 1) / gridDim.x;
  int beg = blockIdx.x * per, end = min(beg + per, E);
  for (int e = beg + tid; e < end; e += 256) {
    int dst = is32 ? ei[E + e] : ei[2 * (E + e)];
    atomicAdd(&h[dst >> 6], 1);
  }
  __syncthreads();
  for (int i = tid; i < nb; i += 256) if (h[i]) atomicAdd(&bcnt[i], h[i]);
}

// ---------------- single-block exclusive scan over nb (<=1024) bucket counts ----------------
__global__ void scan_nb_k(const int* __restrict__ bcnt, int* __restrict__ base,
                          int* __restrict__ cursor, int nb) {
  int tid = threadIdx.x;  // 256
  int i0 = tid * 4;
  int v[4]; int s = 0;
#pragma unroll
  for (int j = 0; j < 4; ++j) { int idx = i0 + j; v[j] = (idx < nb) ? bcnt[idx] : 0; s += v[j]; }
  int lane = tid & 63, w = tid >> 6;
  int sc = s;
  for (int d = 1; d < 64; d <<= 1) { int t = __shfl_up(sc, d); if (lane >= d) sc += t; }
  __shared__ int wsum[4];
  if (lane == 63) wsum[w] = sc;
  __syncthreads();
  int add = 0;
  for (int j = 0; j < w; ++j) add += wsum[j];
  int run = add + (sc - s);
#pragma unroll
  for (int j = 0; j < 4; ++j) {
    int idx = i0 + j;
    if (idx < nb) { base[idx] = run; cursor[idx] = run; }
    run += v[j];
  }
  if (tid == 255) base[nb] = add + sc;  // grand total
}

// ---------------- block-aggregated bucket scatter: tmp[pos] = src | dst_local<<26 ----------------
__global__ void epack_k(const int* __restrict__ ei, int E, const int* __restrict__ is32p,
                        int* __restrict__ cursor, unsigned* __restrict__ tmp, int nb) {
  __shared__ int h[NB_MAX];
  __shared__ int lbase[NB_MAX];
  int tid = threadIdx.x;
  for (int i = tid; i < nb; i += 256) h[i] = 0;
  __syncthreads();
  int is32 = *is32p;
  int per = (E + gridDim.x - 1) / gridDim.x;
  int beg = blockIdx.x * per, end = min(beg + per, E);
  for (int e = beg + tid; e < end; e += 256) {
    int dst = is32 ? ei[E + e] : ei[2 * (E + e)];
    atomicAdd(&h[dst >> 6], 1);
  }
  __syncthreads();
  for (int i = tid; i < nb; i += 256) {
    int c = h[i];
    lbase[i] = c ? atomicAdd(&cursor[i], c) : 0;
    h[i] = 0;  // reuse as local cursor
  }
  __syncthreads();
  for (int e = beg + tid; e < end; e += 256) {
    int src = is32 ? ei[e] : ei[2 * e];
    int dst = is32 ? ei[E + e] : ei[2 * (E + e)];
    int b = dst >> 6;
    int lo = atomicAdd(&h[b], 1);
    tmp[lbase[b] + lo] = (unsigned)src | ((unsigned)(dst & 63) << 26);
  }
}

// ---------------- per-bucket counting-sort: tmp -> per-node CSR + per-node offs ----------------
__global__ void local_sort_k(const unsigned* __restrict__ tmp, const int* __restrict__ base,
                             int* __restrict__ csr, int* __restrict__ offs) {
  __shared__ int cnt[64];
  int b = blockIdx.x;
  int tid = threadIdx.x;  // 256
  int beg = base[b], end = base[b + 1];
  if (tid < 64) cnt[tid] = 0;
  __syncthreads();
  for (int e = beg + tid; e < end; e += 256) {
    unsigned p = tmp[e];
    atomicAdd(&cnt[p >> 26], 1);
  }
  __syncthreads();
  if (tid < 64) {  // wave 0: exclusive scan of 64 counts
    int v = cnt[tid];
    int sc = v;
    for (int d = 1; d < 64; d <<= 1) { int t = __shfl_up(sc, d); if (tid >= d) sc += t; }
    int excl = sc - v;
    offs[b * 64 + tid] = beg + excl;   // per-node start (node = b*64+tid)
    cnt[tid] = excl;                   // reuse as local cursor
  }
  __syncthreads();
  for (int e = beg + tid; e < end; e += 256) {
    unsigned p = tmp[e];
    int d = p >> 26;
    int lo = atomicAdd(&cnt[d], 1);
    csr[beg + lo] = (int)(p & 0x3ffffff);
  }
}

// ---------------- streaming dual GEMM: B in registers, A via async LDS ring ----------------
// H = A@W (fp16), Rout = A@root + bias (fp16). A: [Mpad][K] fp16 PRE-SWIZZLED rows.
// WR: [256][K] fp16 ([W^T;root^T]). Per wave: B-frags (its 64 output cols x K) held in
// VGPRs (K=256: 128 VGPR), read once from L2. A tiles (BM=64, full K) staged by
// global_load_lds into a 3-deep LDS ring; counted s_waitcnt vmcnt(2*CH) + raw s_barrier
// keeps 2 tiles of loads in flight (never drains to 0 -> HBM latency hidden).
// 512 thr = 8 waves: wave w -> (rg=w&1: 32 rows, nq=w>>1: 64 cols).
// mfma_f32_16x16x32_f16; C/D col=lane&15, row=(lane>>4)*4+reg (proven R1-R10).
template <int K>
__launch_bounds__(512, 2)
__global__ void gemm_pw_k(const _Float16* __restrict__ A, const _Float16* __restrict__ WR,
                          const float* __restrict__ bias,
                          _Float16* __restrict__ H, _Float16* __restrict__ Rout,
                          int M, int ntiles) {
  constexpr int NKK = K / 32;   // MFMA k-steps per tile
  constexpr int CH = K / 64;    // global_load_lds chunks per tile (512 thr x 16B)
  constexpr int TH = 64 * K;    // halfs per tile
  __shared__ alignas(16) _Float16 As[3][TH];   // 96 KB (K=256) / 48 KB (K=128)
  const int tid = threadIdx.x;
  const int lane = tid & 63;
  const int w = tid >> 6;
  const int l15 = lane & 15;
  const int hi = lane >> 4;
  const int rg = w & 1;
  const int nq = w >> 1;
  const int G = gridDim.x;

  // B fragments -> registers (each wave reads only its own 64 rows of WR)
  half8 bfr[4][NKK];
#pragma unroll
  for (int nt = 0; nt < 4; ++nt)
#pragma unroll
    for (int kk = 0; kk < NKK; ++kk)
      bfr[nt][kk] = *(const half8*)(WR + (size_t)((nq * 4 + nt) * 16 + l15) * K + kk * 32 + hi * 8);

  float biasv[4];
#pragma unroll
  for (int nt = 0; nt < 4; ++nt)
    biasv[nt] = (nq >= 2) ? bias[nq * 64 + nt * 16 + l15 - 128] : 0.f;

  auto stage = [&](int buf, int tile) {
#pragma unroll
    for (int it = 0; it < CH; ++it) {
      int o = it * 8192 + tid * 16;  // byte offset within tile (linear; A pre-swizzled)
      gload_lds16((const char*)(A + (size_t)tile * TH) + o, (char*)&As[buf][0] + o);
    }
  };

  int t1 = blockIdx.x + G;
  stage(0, blockIdx.x);
  if (t1 < ntiles) stage(1, t1);

  floatx4 acc[2][4];
#pragma unroll
  for (int i = 0; i < 2; ++i)
#pragma unroll
    for (int nt = 0; nt < 4; ++nt) acc[i][nt] = (floatx4)0.f;

  const int swz = (l15 & 7) << 3;  // row-XOR for conflict-free A reads
  int bi = 0;
  for (int tile = blockIdx.x; tile < ntiles; tile += G, ++bi) {
    __builtin_amdgcn_s_barrier();          // all waves done reading buf being re-staged
    asm volatile("" ::: "memory");
    int nxt = tile + 2 * G;
    if (nxt < ntiles) stage((bi + 2) % 3, nxt);
    asm volatile("s_waitcnt vmcnt(%0)" :: "i"(2 * CH) : "memory");  // current buf landed
    __builtin_amdgcn_sched_barrier(0);
    const _Float16* Ab = As[bi % 3];
    const int r0 = rg * 32 + l15;
#pragma unroll
    for (int kk = 0; kk < NKK; ++kk) {
      half8 af0 = *(const half8*)&Ab[r0 * K + ((kk * 32 + hi * 8) ^ swz)];
      half8 af1 = *(const half8*)&Ab[(r0 + 16) * K + ((kk * 32 + hi * 8) ^ swz)];
#pragma unroll
      for (int nt = 0; nt < 4; ++nt) {
        acc[0][nt] = __builtin_amdgcn_mfma_f32_16x16x32_f16(af0, bfr[nt][kk], acc[0][nt], 0, 0, 0);
        acc[1][nt] = __builtin_amdgcn_mfma_f32_16x16x32_f16(af1, bfr[nt][kk], acc[1][nt], 0, 0, 0);
      }
    }
    const int m0 = tile * 64;
#pragma unroll
    for (int i = 0; i < 2; ++i)
#pragma unroll
      for (int nt = 0; nt < 4; ++nt) {
        int n = nq * 64 + nt * 16 + l15;
#pragma unroll
        for (int j = 0; j < 4; ++j) {
          int row = m0 + rg * 32 + i * 16 + hi * 4 + j;
          if (row < M) {
            if (n < 128) H[(size_t)row * 128 + n] = (_Float16)acc[i][nt][j];
            else Rout[(size_t)row * 128 + n - 128] = (_Float16)(acc[i][nt][j] + biasv[nt]);
          }
        }
        acc[i][nt] = (floatx4)0.f;
      }
  }
}

// ---------------- per-node aggregation + mean + root(+bias) (+relu) ----------------
// One block (128 thr) per dst node; thread c owns channel c. unroll-4 MLP.
// SWZ: write output rows pre-swizzled (consumed by gemm_pw_k staging).
template <bool RELU, bool SWZ, typename OutT>
__global__ void agg_node_k(const _Float16* __restrict__ Hh, const _Float16* __restrict__ R,
                           const int* __restrict__ offs, const int* __restrict__ csr,
                           OutT* __restrict__ out) {
  int node = blockIdx.x;
  int c = threadIdx.x;
  int beg = offs[node], end = offs[node + 1];
  float acc = 0.f;
  int e = beg;
  for (; e + 4 <= end; e += 4) {
    int s0 = csr[e], s1 = csr[e + 1], s2 = csr[e + 2], s3 = csr[e + 3];
    float a0 = (float)Hh[(size_t)s0 * 128 + c];
    float a1 = (float)Hh[(size_t)s1 * 128 + c];
    float a2 = (float)Hh[(size_t)s2 * 128 + c];
    float a3 = (float)Hh[(size_t)s3 * 128 + c];
    acc += (a0 + a1) + (a2 + a3);
  }
  for (; e < end; ++e) acc += (float)Hh[(size_t)csr[e] * 128 + c];
  float deg = (float)(end - beg);
  float val = acc / fmaxf(deg, 1.f) + (float)R[(size_t)node * 128 + c];
  if (RELU) val = fmaxf(val, 0.f);
  int cs = SWZ ? (c ^ ((node & 7) << 3)) : c;
  out[(size_t)node * 128 + cs] = (OutT)val;
}

// ---------------- launch ----------------
extern "C" void kernel_launch(void* const* d_in, const int* in_sizes, int n_in,
                              void* d_out, int out_size, void* d_ws, size_t ws_size,
                              hipStream_t stream) {
  const float* x     = (const float*)d_in[0];
  const int*   ei    = (const int*)d_in[1];
  const float* W1    = (const float*)d_in[2];
  const float* root1 = (const float*)d_in[3];
  const float* b1    = (const float*)d_in[4];
  const float* W2    = (const float*)d_in[5];
  const float* root2 = (const float*)d_in[6];
  const float* b2    = (const float*)d_in[7];

  const int M = in_sizes[0] / 256;   // 50000
  const int E = in_sizes[1] / 2;     // 800000
  const int NB = (M + 63) >> 6;      // 782
  const int ntiles = NB;             // 64-row tiles
  const int Mpad = ntiles * 64;      // 50048 (staging reads padded rows; stores masked)

  char* p = (char*)d_ws;
  auto alloc = [&](size_t b) { char* r = p; p += (b + 255) & ~(size_t)255; return r; };
  _Float16* WR1 = (_Float16*)alloc((size_t)256 * 256 * 2);  // [W1^T ; root1^T]
  _Float16* WR2 = (_Float16*)alloc((size_t)256 * 128 * 2);  // [W2^T ; root2^T]
  _Float16* x16 = (_Float16*)alloc((size_t)Mpad * 256 * 2); // pre-swizzled fp16 x
  _Float16* Hh  = (_Float16*)alloc((size_t)Mpad * 128 * 2); // messages (both layers)
  _Float16* Rb  = (_Float16*)alloc((size_t)Mpad * 128 * 2); // root path (both layers)
  _Float16* hh  = (_Float16*)alloc((size_t)Mpad * 128 * 2); // layer-1 act (pre-swizzled)
  int* is32   = (int*)alloc(4);
  int* bcnt   = (int*)alloc((size_t)NB * 4);
  int* base   = (int*)alloc(((size_t)NB + 1) * 4);
  int* cursor = (int*)alloc((size_t)NB * 4);
  int* offs   = (int*)alloc(((size_t)NB * 64 + 64) * 4);    // per-node starts
  unsigned* tmp = (unsigned*)alloc((size_t)E * 4);
  int* csr    = (int*)alloc((size_t)E * 4);

  hipMemsetAsync(is32, 0, 4, stream);
  hipMemsetAsync(bcnt, 0, (size_t)NB * 4, stream);

  detect_i64<<<4, 256, 0, stream>>>(ei, 1024, is32);
  prep_w_k<<<128, 256, 0, stream>>>(W1, WR1, 256);
  prep_w_k<<<128, 256, 0, stream>>>(root1, WR1 + (size_t)128 * 256, 256);
  prep_w_k<<<64, 256, 0, stream>>>(W2, WR2, 128);
  prep_w_k<<<64, 256, 0, stream>>>(root2, WR2 + (size_t)128 * 128, 128);
  cvt_swz_k<<<(M * 32 + 255) / 256, 256, 0, stream>>>(x, x16, M);

  bucket_hist_k<<<256, 256, 0, stream>>>(ei, E, is32, bcnt, NB);
  scan_nb_k<<<1, 256, 0, stream>>>(bcnt, base, cursor, NB);
  epack_k<<<128, 256, 0, stream>>>(ei, E, is32, cursor, tmp, NB);
  local_sort_k<<<NB, 256, 0, stream>>>(tmp, base, csr, offs);

  gemm_pw_k<256><<<256, 512, 0, stream>>>(x16, WR1, b1, Hh, Rb, M, ntiles);
  agg_node_k<true, true, _Float16><<<M, 128, 0, stream>>>(Hh, Rb, offs, csr, hh);
  gemm_pw_k<128><<<512, 512, 0, stream>>>(hh, WR2, b2, Hh, Rb, M, ntiles);
  agg_node_k<false, false, float><<<M, 128, 0, stream>>>(Hh, Rb, offs, csr, (float*)d_out);
}

// Round 12
// 280.016 us; speedup vs baseline: 5.7269x; 1.0689x over previous
//
#include <hip/hip_runtime.h>
#include <cstdint>
#include <cstddef>

typedef __attribute__((ext_vector_type(8))) _Float16 half8;
typedef __attribute__((ext_vector_type(4))) _Float16 half4;
typedef __attribute__((ext_vector_type(4))) float floatx4;

#define NB_MAX 1024  // supports M <= 65536 (M = 50000)

// async global->LDS, 16B per lane (dest = wave-uniform base + lane*16)
__device__ __forceinline__ void gload_lds16(const void* g, void* l) {
  __builtin_amdgcn_global_load_lds(
      (const __attribute__((address_space(1))) uint32_t*)g,
      (__attribute__((address_space(3))) uint32_t*)l, 16, 0, 0);
}

// ---------------- edge dtype detection (int64 vs int32) ----------------
__global__ void detect_i64(const int* __restrict__ ei, int npairs, int* __restrict__ is32) {
  int i = blockIdx.x * blockDim.x + threadIdx.x;
  if (i < npairs && ei[2 * i + 1] != 0) atomicOr(is32, 1);
}

// ---------------- weight prep: [K][128] fp32 -> [128][K] fp16 (transposed) ----------------
__global__ void prep_w_k(const float* __restrict__ W, _Float16* __restrict__ Wt, int K) {
  int i = blockIdx.x * blockDim.x + threadIdx.x;
  if (i < K * 128) {
    int k = i >> 7, n = i & 127;
    Wt[n * K + k] = (_Float16)W[i];
  }
}

// ---------------- x fp32 -> fp16, PRE-SWIZZLED rows (h ^= (row&7)<<3) ----------------
__global__ void cvt_swz_k(const float* __restrict__ in, _Float16* __restrict__ out, int M) {
  int i = blockIdx.x * blockDim.x + threadIdx.x;  // one thread per 8 halfs
  int r = i >> 5, j = i & 31;
  if (r >= M) return;
  const float* s = in + (size_t)r * 256 + j * 8;
  float4 a = *(const float4*)s;
  float4 b = *(const float4*)(s + 4);
  half8 v;
  v[0] = (_Float16)a.x; v[1] = (_Float16)a.y; v[2] = (_Float16)a.z; v[3] = (_Float16)a.w;
  v[4] = (_Float16)b.x; v[5] = (_Float16)b.y; v[6] = (_Float16)b.z; v[7] = (_Float16)b.w;
  int h0 = (j * 8) ^ ((r & 7) << 3);
  *(half8*)(out + (size_t)r * 256 + h0) = v;
}

// ---------------- bucket histogram (bucket = dst >> 6), LDS pre-aggregated ----------------
__global__ void bucket_hist_k(const int* __restrict__ ei, int E, const int* __restrict__ is32p,
                              int* __restrict__ bcnt, int nb) {
  __shared__ int h[NB_MAX];
  int tid = threadIdx.x;
  for (int i = tid; i < nb; i += 256) h[i] = 0;
  __syncthreads();
  int is32 = *is32p;
  int per = (E + gridDim.x - 1) / gridDim.x;
  int beg = blockIdx.x * per, end = min(beg + per, E);
  for (int e = beg + tid; e < end; e += 256) {
    int dst = is32 ? ei[E + e] : ei[2 * (E + e)];
    atomicAdd(&h[dst >> 6], 1);
  }
  __syncthreads();
  for (int i = tid; i < nb; i += 256) if (h[i]) atomicAdd(&bcnt[i], h[i]);
}

// ---------------- single-block exclusive scan over nb (<=1024) bucket counts ----------------
__global__ void scan_nb_k(const int* __restrict__ bcnt, int* __restrict__ base,
                          int* __restrict__ cursor, int nb) {
  int tid = threadIdx.x;  // 256
  int i0 = tid * 4;
  int v[4]; int s = 0;
#pragma unroll
  for (int j = 0; j < 4; ++j) { int idx = i0 + j; v[j] = (idx < nb) ? bcnt[idx] : 0; s += v[j]; }
  int lane = tid & 63, w = tid >> 6;
  int sc = s;
  for (int d = 1; d < 64; d <<= 1) { int t = __shfl_up(sc, d); if (lane >= d) sc += t; }
  __shared__ int wsum[4];
  if (lane == 63) wsum[w] = sc;
  __syncthreads();
  int add = 0;
  for (int j = 0; j < w; ++j) add += wsum[j];
  int run = add + (sc - s);
#pragma unroll
  for (int j = 0; j < 4; ++j) {
    int idx = i0 + j;
    if (idx < nb) { base[idx] = run; cursor[idx] = run; }
    run += v[j];
  }
  if (tid == 255) base[nb] = add + sc;  // grand total
}

// ---------------- block-aggregated bucket scatter: tmp[pos] = src | dst_local<<26 ----------------
__global__ void epack_k(const int* __restrict__ ei, int E, const int* __restrict__ is32p,
                        int* __restrict__ cursor, unsigned* __restrict__ tmp, int nb) {
  __shared__ int h[NB_MAX];
  __shared__ int lbase[NB_MAX];
  int tid = threadIdx.x;
  for (int i = tid; i < nb; i += 256) h[i] = 0;
  __syncthreads();
  int is32 = *is32p;
  int per = (E + gridDim.x - 1) / gridDim.x;
  int beg = blockIdx.x * per, end = min(beg + per, E);
  for (int e = beg + tid; e < end; e += 256) {
    int dst = is32 ? ei[E + e] : ei[2 * (E + e)];
    atomicAdd(&h[dst >> 6], 1);
  }
  __syncthreads();
  for (int i = tid; i < nb; i += 256) {
    int c = h[i];
    lbase[i] = c ? atomicAdd(&cursor[i], c) : 0;
    h[i] = 0;  // reuse as local cursor
  }
  __syncthreads();
  for (int e = beg + tid; e < end; e += 256) {
    int src = is32 ? ei[e] : ei[2 * e];
    int dst = is32 ? ei[E + e] : ei[2 * (E + e)];
    int b = dst >> 6;
    int lo = atomicAdd(&h[b], 1);
    tmp[lbase[b] + lo] = (unsigned)src | ((unsigned)(dst & 63) << 26);
  }
}

// ---------------- per-bucket counting-sort: tmp -> per-node CSR + per-node offs ----------------
__global__ void local_sort_k(const unsigned* __restrict__ tmp, const int* __restrict__ base,
                             int* __restrict__ csr, int* __restrict__ offs) {
  __shared__ int cnt[64];
  int b = blockIdx.x;
  int tid = threadIdx.x;  // 256
  int beg = base[b], end = base[b + 1];
  if (tid < 64) cnt[tid] = 0;
  __syncthreads();
  for (int e = beg + tid; e < end; e += 256) {
    unsigned p = tmp[e];
    atomicAdd(&cnt[p >> 26], 1);
  }
  __syncthreads();
  if (tid < 64) {  // wave 0: exclusive scan of 64 counts
    int v = cnt[tid];
    int sc = v;
    for (int d = 1; d < 64; d <<= 1) { int t = __shfl_up(sc, d); if (tid >= d) sc += t; }
    int excl = sc - v;
    offs[b * 64 + tid] = beg + excl;   // per-node start (node = b*64+tid)
    cnt[tid] = excl;                   // reuse as local cursor
  }
  __syncthreads();
  for (int e = beg + tid; e < end; e += 256) {
    unsigned p = tmp[e];
    int d = p >> 26;
    int lo = atomicAdd(&cnt[d], 1);
    csr[beg + lo] = (int)(p & 0x3ffffff);
  }
}

// ---------------- streaming dual GEMM: B in registers, A via async LDS ring ----------------
// (unchanged from R10 — verified: no longer in top-5)
template <int K>
__launch_bounds__(512, 2)
__global__ void gemm_pw_k(const _Float16* __restrict__ A, const _Float16* __restrict__ WR,
                          const float* __restrict__ bias,
                          _Float16* __restrict__ H, _Float16* __restrict__ Rout,
                          int M, int ntiles) {
  constexpr int NKK = K / 32;
  constexpr int CH = K / 64;
  constexpr int TH = 64 * K;
  __shared__ alignas(16) _Float16 As[3][TH];
  const int tid = threadIdx.x;
  const int lane = tid & 63;
  const int w = tid >> 6;
  const int l15 = lane & 15;
  const int hi = lane >> 4;
  const int rg = w & 1;
  const int nq = w >> 1;
  const int G = gridDim.x;

  half8 bfr[4][NKK];
#pragma unroll
  for (int nt = 0; nt < 4; ++nt)
#pragma unroll
    for (int kk = 0; kk < NKK; ++kk)
      bfr[nt][kk] = *(const half8*)(WR + (size_t)((nq * 4 + nt) * 16 + l15) * K + kk * 32 + hi * 8);

  float biasv[4];
#pragma unroll
  for (int nt = 0; nt < 4; ++nt)
    biasv[nt] = (nq >= 2) ? bias[nq * 64 + nt * 16 + l15 - 128] : 0.f;

  auto stage = [&](int buf, int tile) {
#pragma unroll
    for (int it = 0; it < CH; ++it) {
      int o = it * 8192 + tid * 16;
      gload_lds16((const char*)(A + (size_t)tile * TH) + o, (char*)&As[buf][0] + o);
    }
  };

  int t1 = blockIdx.x + G;
  stage(0, blockIdx.x);
  if (t1 < ntiles) stage(1, t1);

  floatx4 acc[2][4];
#pragma unroll
  for (int i = 0; i < 2; ++i)
#pragma unroll
    for (int nt = 0; nt < 4; ++nt) acc[i][nt] = (floatx4)0.f;

  const int swz = (l15 & 7) << 3;
  int bi = 0;
  for (int tile = blockIdx.x; tile < ntiles; tile += G, ++bi) {
    __builtin_amdgcn_s_barrier();
    asm volatile("" ::: "memory");
    int nxt = tile + 2 * G;
    if (nxt < ntiles) stage((bi + 2) % 3, nxt);
    asm volatile("s_waitcnt vmcnt(%0)" :: "i"(2 * CH) : "memory");
    __builtin_amdgcn_sched_barrier(0);
    const _Float16* Ab = As[bi % 3];
    const int r0 = rg * 32 + l15;
#pragma unroll
    for (int kk = 0; kk < NKK; ++kk) {
      half8 af0 = *(const half8*)&Ab[r0 * K + ((kk * 32 + hi * 8) ^ swz)];
      half8 af1 = *(const half8*)&Ab[(r0 + 16) * K + ((kk * 32 + hi * 8) ^ swz)];
#pragma unroll
      for (int nt = 0; nt < 4; ++nt) {
        acc[0][nt] = __builtin_amdgcn_mfma_f32_16x16x32_f16(af0, bfr[nt][kk], acc[0][nt], 0, 0, 0);
        acc[1][nt] = __builtin_amdgcn_mfma_f32_16x16x32_f16(af1, bfr[nt][kk], acc[1][nt], 0, 0, 0);
      }
    }
    const int m0 = tile * 64;
#pragma unroll
    for (int i = 0; i < 2; ++i)
#pragma unroll
      for (int nt = 0; nt < 4; ++nt) {
        int n = nq * 64 + nt * 16 + l15;
#pragma unroll
        for (int j = 0; j < 4; ++j) {
          int row = m0 + rg * 32 + i * 16 + hi * 4 + j;
          if (row < M) {
            if (n < 128) H[(size_t)row * 128 + n] = (_Float16)acc[i][nt][j];
            else Rout[(size_t)row * 128 + n - 128] = (_Float16)(acc[i][nt][j] + biasv[nt]);
          }
        }
        acc[i][nt] = (floatx4)0.f;
      }
  }
}

// ---------------- per-node aggregation, wave-per-node 8B/lane gather ----------------
// 64 lanes = 2 edge-groups x 32 lanes; lane cl owns channels 4cl..4cl+3 (half4 loads:
// one wave-load = 512B across 2 edge rows). Cross-group combine via shfl_xor(32).
// SWZ: swizzle XOR hits bits 3-5 of half-index only -> half4 stores stay contiguous.
template <bool RELU, bool SWZ, typename OutT>
__global__ void agg_node_k(const _Float16* __restrict__ Hh, const _Float16* __restrict__ R,
                           const int* __restrict__ offs, const int* __restrict__ csr,
                           OutT* __restrict__ out, int M) {
  int node = blockIdx.x * 4 + (threadIdx.x >> 6);
  if (node >= M) return;
  int lane = threadIdx.x & 63;
  int grp = lane >> 5, cl = lane & 31;
  int beg = offs[node], end = offs[node + 1];
  float a0 = 0.f, a1 = 0.f, a2 = 0.f, a3 = 0.f;
  int e = beg + grp;                       // each group strides by 2
  for (; e + 2 < end; e += 4) {            // unroll-2: edges e, e+2 per group
    int s0 = csr[e], s1 = csr[e + 2];
    half4 v0 = *(const half4*)(Hh + (size_t)s0 * 128 + cl * 4);
    half4 v1 = *(const half4*)(Hh + (size_t)s1 * 128 + cl * 4);
    a0 += (float)v0[0] + (float)v1[0];
    a1 += (float)v0[1] + (float)v1[1];
    a2 += (float)v0[2] + (float)v1[2];
    a3 += (float)v0[3] + (float)v1[3];
  }
  for (; e < end; e += 2) {
    int s0 = csr[e];
    half4 v0 = *(const half4*)(Hh + (size_t)s0 * 128 + cl * 4);
    a0 += (float)v0[0]; a1 += (float)v0[1]; a2 += (float)v0[2]; a3 += (float)v0[3];
  }
  // combine the two edge-groups (same channels, disjoint edges)
  a0 += __shfl_xor(a0, 32);
  a1 += __shfl_xor(a1, 32);
  a2 += __shfl_xor(a2, 32);
  a3 += __shfl_xor(a3, 32);
  if (grp == 0) {
    float inv = 1.f / fmaxf((float)(end - beg), 1.f);
    half4 r = *(const half4*)(R + (size_t)node * 128 + cl * 4);
    float v[4] = {a0 * inv + (float)r[0], a1 * inv + (float)r[1],
                  a2 * inv + (float)r[2], a3 * inv + (float)r[3]};
    if (RELU) {
#pragma unroll
      for (int j = 0; j < 4; ++j) v[j] = fmaxf(v[j], 0.f);
    }
    if constexpr (sizeof(OutT) == 4) {
      floatx4 o = {v[0], v[1], v[2], v[3]};
      *(floatx4*)((float*)out + (size_t)node * 128 + cl * 4) = o;
    } else {
      half4 o;
      o[0] = (_Float16)v[0]; o[1] = (_Float16)v[1];
      o[2] = (_Float16)v[2]; o[3] = (_Float16)v[3];
      int c0 = SWZ ? ((cl * 4) ^ ((node & 7) << 3)) : cl * 4;
      *(half4*)((_Float16*)out + (size_t)node * 128 + c0) = o;
    }
  }
}

// ---------------- launch ----------------
extern "C" void kernel_launch(void* const* d_in, const int* in_sizes, int n_in,
                              void* d_out, int out_size, void* d_ws, size_t ws_size,
                              hipStream_t stream) {
  const float* x     = (const float*)d_in[0];
  const int*   ei    = (const int*)d_in[1];
  const float* W1    = (const float*)d_in[2];
  const float* root1 = (const float*)d_in[3];
  const float* b1    = (const float*)d_in[4];
  const float* W2    = (const float*)d_in[5];
  const float* root2 = (const float*)d_in[6];
  const float* b2    = (const float*)d_in[7];

  const int M = in_sizes[0] / 256;   // 50000
  const int E = in_sizes[1] / 2;     // 800000
  const int NB = (M + 63) >> 6;      // 782
  const int ntiles = NB;
  const int Mpad = ntiles * 64;      // 50048

  char* p = (char*)d_ws;
  auto alloc = [&](size_t b) { char* r = p; p += (b + 255) & ~(size_t)255; return r; };
  _Float16* WR1 = (_Float16*)alloc((size_t)256 * 256 * 2);
  _Float16* WR2 = (_Float16*)alloc((size_t)256 * 128 * 2);
  _Float16* x16 = (_Float16*)alloc((size_t)Mpad * 256 * 2);
  _Float16* Hh  = (_Float16*)alloc((size_t)Mpad * 128 * 2);
  _Float16* Rb  = (_Float16*)alloc((size_t)Mpad * 128 * 2);
  _Float16* hh  = (_Float16*)alloc((size_t)Mpad * 128 * 2);
  int* is32   = (int*)alloc(4);
  int* bcnt   = (int*)alloc((size_t)NB * 4);
  int* base   = (int*)alloc(((size_t)NB + 1) * 4);
  int* cursor = (int*)alloc((size_t)NB * 4);
  int* offs   = (int*)alloc(((size_t)NB * 64 + 64) * 4);
  unsigned* tmp = (unsigned*)alloc((size_t)E * 4);
  int* csr    = (int*)alloc((size_t)E * 4);

  hipMemsetAsync(is32, 0, 4, stream);
  hipMemsetAsync(bcnt, 0, (size_t)NB * 4, stream);

  detect_i64<<<4, 256, 0, stream>>>(ei, 1024, is32);
  prep_w_k<<<128, 256, 0, stream>>>(W1, WR1, 256);
  prep_w_k<<<128, 256, 0, stream>>>(root1, WR1 + (size_t)128 * 256, 256);
  prep_w_k<<<64, 256, 0, stream>>>(W2, WR2, 128);
  prep_w_k<<<64, 256, 0, stream>>>(root2, WR2 + (size_t)128 * 128, 128);
  cvt_swz_k<<<(M * 32 + 255) / 256, 256, 0, stream>>>(x, x16, M);

  bucket_hist_k<<<256, 256, 0, stream>>>(ei, E, is32, bcnt, NB);
  scan_nb_k<<<1, 256, 0, stream>>>(bcnt, base, cursor, NB);
  epack_k<<<128, 256, 0, stream>>>(ei, E, is32, cursor, tmp, NB);
  local_sort_k<<<NB, 256, 0, stream>>>(tmp, base, csr, offs);

  gemm_pw_k<256><<<256, 512, 0, stream>>>(x16, WR1, b1, Hh, Rb, M, ntiles);
  agg_node_k<true, true, _Float16><<<(M + 3) / 4, 256, 0, stream>>>(Hh, Rb, offs, csr, hh, M);
  gemm_pw_k<128><<<512, 512, 0, stream>>>(hh, WR2, b2, Hh, Rb, M, ntiles);
  agg_node_k<false, false, float><<<(M + 3) / 4, 256, 0, stream>>>(Hh, Rb, offs, csr, (float*)d_out, M);
}

// Round 14
// 259.612 us; speedup vs baseline: 6.1770x; 1.0786x over previous
//
#include <hip/hip_runtime.h>
#include <cstdint>
#include <cstddef>

typedef __attribute__((ext_vector_type(8))) _Float16 half8;
typedef __attribute__((ext_vector_type(4))) _Float16 half4;
typedef __attribute__((ext_vector_type(4))) float floatx4;

#define NB_MAX 1024  // supports M <= 65536 (M = 50000)

// async global->LDS, 16B per lane (dest = wave-uniform base + lane*16)
__device__ __forceinline__ void gload_lds16(const void* g, void* l) {
  __builtin_amdgcn_global_load_lds(
      (const __attribute__((address_space(1))) uint32_t*)g,
      (__attribute__((address_space(3))) uint32_t*)l, 16, 0, 0);
}

// ---------------- fused prologue: zero flags + dtype detect + 4x weight transpose ----------------
// Block 0: zero is32/bcnt, then int64-vs-int32 detect (odd words all zero => int64).
// Blocks 1..: [K][128] fp32 -> [128][K] fp16 transposes for W1/root1/W2/root2.
__global__ void prep_all_k(const int* __restrict__ ei,
                           const float* __restrict__ W1, const float* __restrict__ root1,
                           const float* __restrict__ W2, const float* __restrict__ root2,
                           _Float16* __restrict__ WR1, _Float16* __restrict__ WR2,
                           int* __restrict__ is32, int* __restrict__ bcnt, int nb) {
  int tid = threadIdx.x;
  if (blockIdx.x == 0) {
    for (int i = tid; i < nb; i += 256) bcnt[i] = 0;
    if (tid == 0) *is32 = 0;
    __syncthreads();
    for (int i = tid; i < 1024; i += 256)
      if (ei[2 * i + 1] != 0) atomicOr(is32, 1);
  } else {
    const int total = 32768 + 32768 + 16384 + 16384;
    for (int i = (blockIdx.x - 1) * 256 + tid; i < total; i += (gridDim.x - 1) * 256) {
      if (i < 32768) {
        int k = i >> 7, n = i & 127;
        WR1[n * 256 + k] = (_Float16)W1[i];
      } else if (i < 65536) {
        int j = i - 32768, k = j >> 7, n = j & 127;
        WR1[32768 + n * 256 + k] = (_Float16)root1[j];
      } else if (i < 81920) {
        int j = i - 65536, k = j >> 7, n = j & 127;
        WR2[n * 128 + k] = (_Float16)W2[j];
      } else {
        int j = i - 81920, k = j >> 7, n = j & 127;
        WR2[16384 + n * 128 + k] = (_Float16)root2[j];
      }
    }
  }
}

// ---------------- x fp32 -> fp16, PRE-SWIZZLED rows (h ^= (row&7)<<3) ----------------
__global__ void cvt_swz_k(const float* __restrict__ in, _Float16* __restrict__ out, int M) {
  int i = blockIdx.x * blockDim.x + threadIdx.x;  // one thread per 8 halfs
  int r = i >> 5, j = i & 31;
  if (r >= M) return;
  const float* s = in + (size_t)r * 256 + j * 8;
  float4 a = *(const float4*)s;
  float4 b = *(const float4*)(s + 4);
  half8 v;
  v[0] = (_Float16)a.x; v[1] = (_Float16)a.y; v[2] = (_Float16)a.z; v[3] = (_Float16)a.w;
  v[4] = (_Float16)b.x; v[5] = (_Float16)b.y; v[6] = (_Float16)b.z; v[7] = (_Float16)b.w;
  int h0 = (j * 8) ^ ((r & 7) << 3);
  *(half8*)(out + (size_t)r * 256 + h0) = v;
}

// ---------------- bucket histogram (bucket = dst >> 6), LDS pre-aggregated ----------------
__global__ void bucket_hist_k(const int* __restrict__ ei, int E, const int* __restrict__ is32p,
                              int* __restrict__ bcnt, int nb) {
  __shared__ int h[NB_MAX];
  int tid = threadIdx.x;
  for (int i = tid; i < nb; i += 256) h[i] = 0;
  __syncthreads();
  int is32 = *is32p;
  int per = (E + gridDim.x - 1) / gridDim.x;
  int beg = blockIdx.x * per, end = min(beg + per, E);
  for (int e = beg + tid; e < end; e += 256) {
    int dst = is32 ? ei[E + e] : ei[2 * (E + e)];
    atomicAdd(&h[dst >> 6], 1);
  }
  __syncthreads();
  for (int i = tid; i < nb; i += 256) if (h[i]) atomicAdd(&bcnt[i], h[i]);
}

// ---------------- single-block exclusive scan over nb (<=1024) bucket counts ----------------
__global__ void scan_nb_k(const int* __restrict__ bcnt, int* __restrict__ base,
                          int* __restrict__ cursor, int nb) {
  int tid = threadIdx.x;  // 256
  int i0 = tid * 4;
  int v[4]; int s = 0;
#pragma unroll
  for (int j = 0; j < 4; ++j) { int idx = i0 + j; v[j] = (idx < nb) ? bcnt[idx] : 0; s += v[j]; }
  int lane = tid & 63, w = tid >> 6;
  int sc = s;
  for (int d = 1; d < 64; d <<= 1) { int t = __shfl_up(sc, d); if (lane >= d) sc += t; }
  __shared__ int wsum[4];
  if (lane == 63) wsum[w] = sc;
  __syncthreads();
  int add = 0;
  for (int j = 0; j < w; ++j) add += wsum[j];
  int run = add + (sc - s);
#pragma unroll
  for (int j = 0; j < 4; ++j) {
    int idx = i0 + j;
    if (idx < nb) { base[idx] = run; cursor[idx] = run; }
    run += v[j];
  }
  if (tid == 255) base[nb] = add + sc;  // grand total
}

// ---------------- block-aggregated bucket scatter: tmp[pos] = src | dst_local<<26 ----------------
__global__ void epack_k(const int* __restrict__ ei, int E, const int* __restrict__ is32p,
                        int* __restrict__ cursor, unsigned* __restrict__ tmp, int nb) {
  __shared__ int h[NB_MAX];
  __shared__ int lbase[NB_MAX];
  int tid = threadIdx.x;
  for (int i = tid; i < nb; i += 256) h[i] = 0;
  __syncthreads();
  int is32 = *is32p;
  int per = (E + gridDim.x - 1) / gridDim.x;
  int beg = blockIdx.x * per, end = min(beg + per, E);
  for (int e = beg + tid; e < end; e += 256) {
    int dst = is32 ? ei[E + e] : ei[2 * (E + e)];
    atomicAdd(&h[dst >> 6], 1);
  }
  __syncthreads();
  for (int i = tid; i < nb; i += 256) {
    int c = h[i];
    lbase[i] = c ? atomicAdd(&cursor[i], c) : 0;
    h[i] = 0;  // reuse as local cursor
  }
  __syncthreads();
  for (int e = beg + tid; e < end; e += 256) {
    int src = is32 ? ei[e] : ei[2 * e];
    int dst = is32 ? ei[E + e] : ei[2 * (E + e)];
    int b = dst >> 6;
    int lo = atomicAdd(&h[b], 1);
    tmp[lbase[b] + lo] = (unsigned)src | ((unsigned)(dst & 63) << 26);
  }
}

// ---------------- per-bucket counting-sort: tmp -> per-node CSR + per-node offs ----------------
__global__ void local_sort_k(const unsigned* __restrict__ tmp, const int* __restrict__ base,
                             int* __restrict__ csr, int* __restrict__ offs) {
  __shared__ int cnt[64];
  int b = blockIdx.x;
  int tid = threadIdx.x;  // 256
  int beg = base[b], end = base[b + 1];
  if (tid < 64) cnt[tid] = 0;
  __syncthreads();
  for (int e = beg + tid; e < end; e += 256) {
    unsigned p = tmp[e];
    atomicAdd(&cnt[p >> 26], 1);
  }
  __syncthreads();
  if (tid < 64) {  // wave 0: exclusive scan of 64 counts
    int v = cnt[tid];
    int sc = v;
    for (int d = 1; d < 64; d <<= 1) { int t = __shfl_up(sc, d); if (tid >= d) sc += t; }
    int excl = sc - v;
    offs[b * 64 + tid] = beg + excl;   // per-node start (node = b*64+tid)
    cnt[tid] = excl;                   // reuse as local cursor
  }
  __syncthreads();
  for (int e = beg + tid; e < end; e += 256) {
    unsigned p = tmp[e];
    int d = p >> 26;
    int lo = atomicAdd(&cnt[d], 1);
    csr[beg + lo] = (int)(p & 0x3ffffff);
  }
}

// ---------------- streaming dual GEMM: B in registers, A via async LDS ring ----------------
// (unchanged from R10/R11 — verified out of top-5)
template <int K>
__launch_bounds__(512, 2)
__global__ void gemm_pw_k(const _Float16* __restrict__ A, const _Float16* __restrict__ WR,
                          const float* __restrict__ bias,
                          _Float16* __restrict__ H, _Float16* __restrict__ Rout,
                          int M, int ntiles) {
  constexpr int NKK = K / 32;
  constexpr int CH = K / 64;
  constexpr int TH = 64 * K;
  __shared__ alignas(16) _Float16 As[3][TH];
  const int tid = threadIdx.x;
  const int lane = tid & 63;
  const int w = tid >> 6;
  const int l15 = lane & 15;
  const int hi = lane >> 4;
  const int rg = w & 1;
  const int nq = w >> 1;
  const int G = gridDim.x;

  half8 bfr[4][NKK];
#pragma unroll
  for (int nt = 0; nt < 4; ++nt)
#pragma unroll
    for (int kk = 0; kk < NKK; ++kk)
      bfr[nt][kk] = *(const half8*)(WR + (size_t)((nq * 4 + nt) * 16 + l15) * K + kk * 32 + hi * 8);

  float biasv[4];
#pragma unroll
  for (int nt = 0; nt < 4; ++nt)
    biasv[nt] = (nq >= 2) ? bias[nq * 64 + nt * 16 + l15 - 128] : 0.f;

  auto stage = [&](int buf, int tile) {
#pragma unroll
    for (int it = 0; it < CH; ++it) {
      int o = it * 8192 + tid * 16;
      gload_lds16((const char*)(A + (size_t)tile * TH) + o, (char*)&As[buf][0] + o);
    }
  };

  int t1 = blockIdx.x + G;
  stage(0, blockIdx.x);
  if (t1 < ntiles) stage(1, t1);

  floatx4 acc[2][4];
#pragma unroll
  for (int i = 0; i < 2; ++i)
#pragma unroll
    for (int nt = 0; nt < 4; ++nt) acc[i][nt] = (floatx4)0.f;

  const int swz = (l15 & 7) << 3;
  int bi = 0;
  for (int tile = blockIdx.x; tile < ntiles; tile += G, ++bi) {
    __builtin_amdgcn_s_barrier();
    asm volatile("" ::: "memory");
    int nxt = tile + 2 * G;
    if (nxt < ntiles) stage((bi + 2) % 3, nxt);
    asm volatile("s_waitcnt vmcnt(%0)" :: "i"(2 * CH) : "memory");
    __builtin_amdgcn_sched_barrier(0);
    const _Float16* Ab = As[bi % 3];
    const int r0 = rg * 32 + l15;
#pragma unroll
    for (int kk = 0; kk < NKK; ++kk) {
      half8 af0 = *(const half8*)&Ab[r0 * K + ((kk * 32 + hi * 8) ^ swz)];
      half8 af1 = *(const half8*)&Ab[(r0 + 16) * K + ((kk * 32 + hi * 8) ^ swz)];
#pragma unroll
      for (int nt = 0; nt < 4; ++nt) {
        acc[0][nt] = __builtin_amdgcn_mfma_f32_16x16x32_f16(af0, bfr[nt][kk], acc[0][nt], 0, 0, 0);
        acc[1][nt] = __builtin_amdgcn_mfma_f32_16x16x32_f16(af1, bfr[nt][kk], acc[1][nt], 0, 0, 0);
      }
    }
    const int m0 = tile * 64;
#pragma unroll
    for (int i = 0; i < 2; ++i)
#pragma unroll
      for (int nt = 0; nt < 4; ++nt) {
        int n = nq * 64 + nt * 16 + l15;
#pragma unroll
        for (int j = 0; j < 4; ++j) {
          int row = m0 + rg * 32 + i * 16 + hi * 4 + j;
          if (row < M) {
            if (n < 128) H[(size_t)row * 128 + n] = (_Float16)acc[i][nt][j];
            else Rout[(size_t)row * 128 + n - 128] = (_Float16)(acc[i][nt][j] + biasv[nt]);
          }
        }
        acc[i][nt] = (floatx4)0.f;
      }
  }
}

// ---------------- per-node aggregation, wave-per-node 16B/lane gather ----------------
// 64 lanes = 4 edge-groups x 16 lanes; lane cl owns channels 8cl..8cl+7 (half8 loads:
// one wave-load = 1KB across 4 edge rows). unroll-2 => 8 row-loads in flight per wave.
// Cross-group combine: shfl_xor(16) then shfl_xor(32). Lanes 0-15 write results.
// SWZ: XOR hits half-index bits 3-5 only -> half8 stores stay contiguous.
template <bool RELU, bool SWZ, typename OutT>
__global__ void agg_node_k(const _Float16* __restrict__ Hh, const _Float16* __restrict__ R,
                           const int* __restrict__ offs, const int* __restrict__ csr,
                           OutT* __restrict__ out, int M) {
  int node = blockIdx.x * 4 + (threadIdx.x >> 6);
  if (node >= M) return;
  int lane = threadIdx.x & 63;
  int grp = lane >> 4, cl = lane & 15;
  int beg = offs[node], end = offs[node + 1];
  float a[8];
#pragma unroll
  for (int j = 0; j < 8; ++j) a[j] = 0.f;
  int e = beg + grp;                       // each group strides by 4
  for (; e + 4 < end; e += 8) {            // unroll-2: edges e, e+4 per group
    int s0 = csr[e], s1 = csr[e + 4];
    half8 v0 = *(const half8*)(Hh + (size_t)s0 * 128 + cl * 8);
    half8 v1 = *(const half8*)(Hh + (size_t)s1 * 128 + cl * 8);
#pragma unroll
    for (int j = 0; j < 8; ++j) a[j] += (float)v0[j] + (float)v1[j];
  }
  for (; e < end; e += 4) {
    int s0 = csr[e];
    half8 v0 = *(const half8*)(Hh + (size_t)s0 * 128 + cl * 8);
#pragma unroll
    for (int j = 0; j < 8; ++j) a[j] += (float)v0[j];
  }
  // combine the four edge-groups (same channels, disjoint edges)
#pragma unroll
  for (int j = 0; j < 8; ++j) {
    a[j] += __shfl_xor(a[j], 16);
    a[j] += __shfl_xor(a[j], 32);
  }
  if (grp == 0) {
    float inv = 1.f / fmaxf((float)(end - beg), 1.f);
    half8 r = *(const half8*)(R + (size_t)node * 128 + cl * 8);
    float v[8];
#pragma unroll
    for (int j = 0; j < 8; ++j) {
      v[j] = a[j] * inv + (float)r[j];
      if (RELU) v[j] = fmaxf(v[j], 0.f);
    }
    if constexpr (sizeof(OutT) == 4) {
      floatx4 o0 = {v[0], v[1], v[2], v[3]};
      floatx4 o1 = {v[4], v[5], v[6], v[7]};
      float* op = (float*)out + (size_t)node * 128 + cl * 8;
      *(floatx4*)op = o0;
      *(floatx4*)(op + 4) = o1;
    } else {
      half8 o;
#pragma unroll
      for (int j = 0; j < 8; ++j) o[j] = (_Float16)v[j];
      int c0 = SWZ ? ((cl * 8) ^ ((node & 7) << 3)) : cl * 8;
      *(half8*)((_Float16*)out + (size_t)node * 128 + c0) = o;
    }
  }
}

// ---------------- launch ----------------
extern "C" void kernel_launch(void* const* d_in, const int* in_sizes, int n_in,
                              void* d_out, int out_size, void* d_ws, size_t ws_size,
                              hipStream_t stream) {
  const float* x     = (const float*)d_in[0];
  const int*   ei    = (const int*)d_in[1];
  const float* W1    = (const float*)d_in[2];
  const float* root1 = (const float*)d_in[3];
  const float* b1    = (const float*)d_in[4];
  const float* W2    = (const float*)d_in[5];
  const float* root2 = (const float*)d_in[6];
  const float* b2    = (const float*)d_in[7];

  const int M = in_sizes[0] / 256;   // 50000
  const int E = in_sizes[1] / 2;     // 800000
  const int NB = (M + 63) >> 6;      // 782
  const int ntiles = NB;
  const int Mpad = ntiles * 64;      // 50048

  char* p = (char*)d_ws;
  auto alloc = [&](size_t b) { char* r = p; p += (b + 255) & ~(size_t)255; return r; };
  _Float16* WR1 = (_Float16*)alloc((size_t)256 * 256 * 2);
  _Float16* WR2 = (_Float16*)alloc((size_t)256 * 128 * 2);
  _Float16* x16 = (_Float16*)alloc((size_t)Mpad * 256 * 2);
  _Float16* Hh  = (_Float16*)alloc((size_t)Mpad * 128 * 2);
  _Float16* Rb  = (_Float16*)alloc((size_t)Mpad * 128 * 2);
  _Float16* hh  = (_Float16*)alloc((size_t)Mpad * 128 * 2);
  int* is32   = (int*)alloc(4);
  int* bcnt   = (int*)alloc((size_t)NB * 4);
  int* base   = (int*)alloc(((size_t)NB + 1) * 4);
  int* cursor = (int*)alloc((size_t)NB * 4);
  int* offs   = (int*)alloc(((size_t)NB * 64 + 64) * 4);
  unsigned* tmp = (unsigned*)alloc((size_t)E * 4);
  int* csr    = (int*)alloc((size_t)E * 4);

  prep_all_k<<<65, 256, 0, stream>>>(ei, W1, root1, W2, root2, WR1, WR2, is32, bcnt, NB);
  cvt_swz_k<<<(M * 32 + 255) / 256, 256, 0, stream>>>(x, x16, M);

  bucket_hist_k<<<256, 256, 0, stream>>>(ei, E, is32, bcnt, NB);
  scan_nb_k<<<1, 256, 0, stream>>>(bcnt, base, cursor, NB);
  epack_k<<<128, 256, 0, stream>>>(ei, E, is32, cursor, tmp, NB);
  local_sort_k<<<NB, 256, 0, stream>>>(tmp, base, csr, offs);

  gemm_pw_k<256><<<256, 512, 0, stream>>>(x16, WR1, b1, Hh, Rb, M, ntiles);
  agg_node_k<true, true, _Float16><<<(M + 3) / 4, 256, 0, stream>>>(Hh, Rb, offs, csr, hh, M);
  gemm_pw_k<128><<<512, 512, 0, stream>>>(hh, WR2, b2, Hh, Rb, M, ntiles);
  agg_node_k<false, false, float><<<(M + 3) / 4, 256, 0, stream>>>(Hh, Rb, offs, csr, (float*)d_out, M);
}